// Round 10
// baseline (1009.032 us; speedup 1.0000x reference)
//
#include <hip/hip_runtime.h>
#include <hip/hip_bf16.h>
#include <stdint.h>

typedef unsigned short ushort_t;
typedef __bf16 bf16x8 __attribute__((ext_vector_type(8)));
typedef float    f32x4 __attribute__((ext_vector_type(4)));
typedef float   f32x16 __attribute__((ext_vector_type(16)));
typedef unsigned short us4 __attribute__((ext_vector_type(4)));
typedef unsigned int ui4 __attribute__((ext_vector_type(4)));

#define QK_SCALE 0.12751744f   /* log2(e) / sqrt(128) : folded into Q so softmax uses exp2 */
#define NEG_BIG  -1e30f

__device__ __forceinline__ unsigned short f2bf(float f) {
    union { float f; unsigned int u; } v; v.f = f;
    unsigned int u = v.u;
    return (unsigned short)((u + 0x7FFFu + ((u >> 16) & 1u)) >> 16);  // RNE
}

// HW packed convert: dst.lo = bf16(a), dst.hi = bf16(b)
__device__ __forceinline__ unsigned int pk2bf(float a, float b) {
    unsigned int r;
    asm("v_cvt_pk_bf16_f32 %0, %1, %2" : "=v"(r) : "v"(a), "v"(b));
    return r;
}

// async global->LDS, 16B per lane. LDS dest is wave-uniform base + lane*16.
__device__ __forceinline__ void gload16(const void* g, void* l) {
    __builtin_amdgcn_global_load_lds(
        (__attribute__((address_space(1))) void*)(uintptr_t)g,
        (__attribute__((address_space(3))) void*)(uint32_t)(uintptr_t)l,
        16, 0, 0);
}

// ---------------- prep kernels ----------------

__global__ __launch_bounds__(256) void cvt_bf16_kernel(
    const float4* __restrict__ in, us4* __restrict__ out, int n4) {
    int i = blockIdx.x * 256 + threadIdx.x;
    if (i >= n4) return;
    float4 v = in[i];
    us4 o; o[0] = f2bf(v.x); o[1] = f2bf(v.y); o[2] = f2bf(v.z); o[3] = f2bf(v.w);
    out[i] = o;
}

// in [R][C] fp32  ->  out [C][R] bf16   (64x64 LDS tile transpose)
__global__ __launch_bounds__(256) void transpose_bf16(
    const float* __restrict__ in, ushort_t* __restrict__ out, int R, int C) {
    __shared__ float t[64][65];
    int c0 = blockIdx.x * 64, r0 = blockIdx.y * 64;
    int cc = threadIdx.x & 63, rr = threadIdx.x >> 6;
#pragma unroll
    for (int i = 0; i < 16; ++i) {
        int r = i * 4 + rr;
        t[r][cc] = in[(size_t)(r0 + r) * C + c0 + cc];
    }
    __syncthreads();
#pragma unroll
    for (int i = 0; i < 16; ++i) {
        int r = i * 4 + rr;
        out[(size_t)(c0 + r) * R + r0 + cc] = f2bf(t[cc][r]);
    }
}

// rope table: [L][64] of (cos, sin)
__global__ __launch_bounds__(256) void rope_table_kernel(float2* __restrict__ rope) {
    int i = blockIdx.x * 256 + threadIdx.x;     // L*64 = 131072 exactly
    int l = i >> 6, j = i & 63;
    float inv = exp2f((float)j * -0.20762050593046f);  // 10000^(-j/64)
    float f = (float)l * inv;
    rope[i] = make_float2(cosf(f), sinf(f));
}

// ---------------- GEMM (proven 128^2):  C = A * Bt^T  (bf16 in, fp32 acc) ----------------

template <int EPI>
__global__ __launch_bounds__(256, 2)
void gemm_bt(const ushort_t* __restrict__ A, const ushort_t* __restrict__ Bt,
             int M, int N, int K,
             float* __restrict__ C,
             ushort_t* __restrict__ Qb, ushort_t* __restrict__ Kb,
             ushort_t* __restrict__ Vt, const float2* __restrict__ rope) {
    constexpr int MI = (EPI == 1) ? 2 : 4;
    constexpr int NI = (EPI == 1) ? 8 : 4;

    __shared__ __attribute__((aligned(16))) ushort_t ldsA[128 * 64];
    __shared__ __attribute__((aligned(16))) ushort_t ldsB[128 * 64];
    char* ldsAc = (char*)ldsA;
    char* ldsBc = (char*)ldsB;

    const int tid  = threadIdx.x;
    const int lane = tid & 63, wid = tid >> 6;
    const int lr = lane & 15, lg = lane >> 4;

    const int nbn = N >> 7;
    const int nwg = gridDim.x;
    const int bid = blockIdx.x;
    const int wg  = (bid & 7) * (nwg >> 3) + (bid >> 3);   // XCD-contiguous chunks
    const int bm  = wg / nbn, bn = wg % nbn;

    const int arow0 = (EPI == 1) ? wid * 32 : (wid >> 1) * 64;
    const int bcol0 = (EPI == 1) ? 0        : (wid & 1) * 64;

    const int colb = ((tid & 7) << 4) ^ (((tid >> 3) & 7) << 4);
    const int rowi = tid >> 3;                       // 0..31
    const char* Ap = (const char*)A + ((size_t)(bm * 128 + rowi) * K) * 2 + colb;
    const char* Bp = (const char*)Bt + ((size_t)(bn * 128 + rowi) * K) * 2 + colb;
    const size_t rstr = (size_t)32 * K * 2;
    char* ldA = ldsAc + wid * 1024;
    char* ldB = ldsBc + wid * 1024;

    f32x4 acc[MI][NI];
#pragma unroll
    for (int i = 0; i < MI; ++i)
#pragma unroll
        for (int j = 0; j < NI; ++j) acc[i][j] = (f32x4){0.f, 0.f, 0.f, 0.f};

    for (int k0 = 0; k0 < K; k0 += 64) {
#pragma unroll
        for (int r = 0; r < 4; ++r) {
            gload16(Ap + r * rstr + (size_t)k0 * 2, ldA + r * 4096);
            gload16(Bp + r * rstr + (size_t)k0 * 2, ldB + r * 4096);
        }
        __syncthreads();
#pragma unroll
        for (int kk = 0; kk < 2; ++kk) {
            bf16x8 af[MI], bfv[NI];
#pragma unroll
            for (int mi = 0; mi < MI; ++mi) {
                int row = arow0 + mi * 16 + lr;
                int off = (row << 7) + kk * 64 + lg * 16;
                off ^= (row & 7) << 4;
                af[mi] = *(const bf16x8*)(ldsAc + off);
            }
#pragma unroll
            for (int ni = 0; ni < NI; ++ni) {
                int row = bcol0 + ni * 16 + lr;
                int off = (row << 7) + kk * 64 + lg * 16;
                off ^= (row & 7) << 4;
                bfv[ni] = *(const bf16x8*)(ldsBc + off);
            }
#pragma unroll
            for (int mi = 0; mi < MI; ++mi)
#pragma unroll
                for (int ni = 0; ni < NI; ++ni)
                    acc[mi][ni] = __builtin_amdgcn_mfma_f32_16x16x32_bf16(
                        af[mi], bfv[ni], acc[mi][ni], 0, 0, 0);
        }
        __syncthreads();
    }

    if constexpr (EPI == 0) {
#pragma unroll
        for (int mi = 0; mi < MI; ++mi) {
            int gr0 = bm * 128 + arow0 + mi * 16 + lg * 4;
#pragma unroll
            for (int ni = 0; ni < NI; ++ni) {
                int gc = bn * 128 + bcol0 + ni * 16 + lr;
#pragma unroll
                for (int r = 0; r < 4; ++r)
                    C[(size_t)(gr0 + r) * N + gc] = acc[mi][ni][r];
            }
        }
    } else {
        const int which = bn >> 4, h = bn & 15;
#pragma unroll
        for (int mi = 0; mi < MI; ++mi) {
            int gr0 = bm * 128 + arow0 + mi * 16 + lg * 4;   // = b*L + l0 (4 consecutive l)
            int b = gr0 >> 11, l0 = gr0 & 2047;
            if (which == 2) {                                 // V -> [BH][D][L] (transposed)
#pragma unroll
                for (int ni = 0; ni < NI; ++ni) {
                    int d = ni * 16 + lr;
                    us4 pk;
#pragma unroll
                    for (int r = 0; r < 4; ++r) pk[r] = f2bf(acc[mi][ni][r]);
                    *(us4*)(Vt + ((size_t)(b * 16 + h) * 128 + d) * 2048 + l0) = pk;
                }
            } else {                                          // Q/K: rope, -> [BH][L][D]
                ushort_t* dst = (which == 0) ? Qb : Kb;
                const float sc = (which == 0) ? QK_SCALE : 1.0f;
#pragma unroll
                for (int ni = 0; ni < 4; ++ni) {
                    int j = ni * 16 + lr;                     // d < 64 ; pair at d+64 = frag ni+4
#pragma unroll
                    for (int r = 0; r < 4; ++r) {
                        float2 cs = rope[(size_t)(l0 + r) * 64 + j];
                        float x1 = acc[mi][ni][r], x2 = acc[mi][ni + 4][r];
                        size_t base = ((size_t)(b * 16 + h) * 2048 + (l0 + r)) * 128;
                        dst[base + j]      = f2bf((x1 * cs.x - x2 * cs.y) * sc);
                        dst[base + j + 64] = f2bf((x2 * cs.x + x1 * cs.y) * sc);
                    }
                }
            }
        }
    }
}

// ---------------- causal flash attention: KBLK=64 (halved serial-softmax sections) ------
// Q,K: [BH][L][128] bf16 (Q pre-scaled); V^T: [BH][128][L] bf16; AO: [B][L][H*128] bf16.
// One wave per block, one 32-row q-slice; K-tile = 64 rows = two 32-row halves sharing ONE
// softmax/pack/exchange section. Diagonal half masks crow>q_l; even slices skip upper half.
// K(t+1) prefetched (both halves) after S-MFMAs; V in two 8-frag batches.

__global__ __attribute__((amdgpu_flat_work_group_size(64, 64), amdgpu_waves_per_eu(2, 2)))
void attn_fwd(const ushort_t* __restrict__ Qb, const ushort_t* __restrict__ Kb,
              const ushort_t* __restrict__ Vt, ushort_t* __restrict__ AO) {
    constexpr int L = 2048;
    const int lane = threadIdx.x;
    const int q_l  = lane & 31;
    const int hi   = lane >> 5;

    // 4096 blocks: xcd = bid&7, heads 0..7 per xcd, rank 0..63 -> sl = 63-rank (longest first)
    const int bid  = blockIdx.x;
    const int j    = bid >> 3;
    const int hl   = j & 7;
    const int rank = j >> 3;
    const int head = (bid & 7) * 8 + hl;
    const int sl   = 63 - rank;
    const int q0   = sl * 32;

    const ushort_t* Qh = Qb + (size_t)head * L * 128;
    const ushort_t* Kh = Kb + (size_t)head * L * 128;
    const ushort_t* Vh = Vt + (size_t)head * 128 * L;
    const int b = head >> 4, h = head & 15;

    bf16x8 qf[8];
#pragma unroll
    for (int sb = 0; sb < 8; ++sb)
        qf[sb] = *(const bf16x8*)(Qh + (size_t)(q0 + q_l) * 128 + sb * 16 + hi * 8);

    f32x16 o[4];
#pragma unroll
    for (int d0 = 0; d0 < 4; ++d0) o[d0] = (f32x16)(0.f);
    float m_ = -__builtin_inff(), l_ = 0.f;

    const int  nt  = (sl >> 1) + 1;
    const bool odd = (sl & 1) != 0;

    // K tile 0 preload (both halves)
    bf16x8 kf0[8], kf1[8];
#pragma unroll
    for (int sb = 0; sb < 8; ++sb) {
        kf0[sb] = *(const bf16x8*)(Kh + (size_t)(q_l) * 128 + sb * 16 + hi * 8);
        kf1[sb] = *(const bf16x8*)(Kh + (size_t)(32 + q_l) * 128 + sb * 16 + hi * 8);
    }

    for (int t = 0; t < nt; ++t) {
        const int  k0   = t * 64;
        const bool last = (t == nt - 1);
        const bool doh1 = !(last && !odd);

        // V batch 1 (ks=0,1): cover = S-MFMAs + softmax
        bf16x8 vf0[8];
#pragma unroll
        for (int d0 = 0; d0 < 4; ++d0)
#pragma unroll
            for (int ks = 0; ks < 2; ++ks)
                vf0[d0 * 2 + ks] = *(const bf16x8*)(Vh + (size_t)(d0 * 32 + q_l) * L + k0 + ks * 16 + hi * 8);

        // S0 = K[k0..k0+32) * Q^T (two accumulator chains)
        __builtin_amdgcn_s_setprio(1);
        f32x16 sA = (f32x16)(0.f), sB = (f32x16)(0.f);
#pragma unroll
        for (int sb = 0; sb < 8; sb += 2) {
            sA = __builtin_amdgcn_mfma_f32_32x32x16_bf16(kf0[sb],     qf[sb],     sA, 0, 0, 0);
            sB = __builtin_amdgcn_mfma_f32_32x32x16_bf16(kf0[sb + 1], qf[sb + 1], sB, 0, 0, 0);
        }
        f32x16 s0 = sA + sB;
        __builtin_amdgcn_s_setprio(0);

        f32x16 s1;
        if (doh1) {
            __builtin_amdgcn_s_setprio(1);
            f32x16 tA = (f32x16)(0.f), tB = (f32x16)(0.f);
#pragma unroll
            for (int sb = 0; sb < 8; sb += 2) {
                tA = __builtin_amdgcn_mfma_f32_32x32x16_bf16(kf1[sb],     qf[sb],     tA, 0, 0, 0);
                tB = __builtin_amdgcn_mfma_f32_32x32x16_bf16(kf1[sb + 1], qf[sb + 1], tB, 0, 0, 0);
            }
            s1 = tA + tB;
            __builtin_amdgcn_s_setprio(0);
        }

        // K(t+1) prefetch, both halves: cover = softmax + pack + PV
        if (t + 1 < nt) {
            const int kn = k0 + 64;
#pragma unroll
            for (int sb = 0; sb < 8; ++sb) {
                kf0[sb] = *(const bf16x8*)(Kh + (size_t)(kn + q_l) * 128 + sb * 16 + hi * 8);
                kf1[sb] = *(const bf16x8*)(Kh + (size_t)(kn + 32 + q_l) * 128 + sb * 16 + hi * 8);
            }
        }

        // causal mask on the diagonal half (k-base == q0 there; mask crow > q_l)
        if (last) {
            if (odd) {
#pragma unroll
                for (int r = 0; r < 16; ++r) {
                    int crow = (r & 3) + 8 * (r >> 2) + 4 * hi;
                    if (crow > q_l) s1[r] = NEG_BIG;
                }
            } else {
#pragma unroll
                for (int r = 0; r < 16; ++r) {
                    int crow = (r & 3) + 8 * (r >> 2) + 4 * hi;
                    if (crow > q_l) s0[r] = NEG_BIG;
                }
            }
        }

        // ---- one softmax section per 64 k ----
        float t8[8];
#pragma unroll
        for (int r = 0; r < 8; ++r) t8[r] = fmaxf(s0[r], s0[r + 8]);
        if (doh1)
#pragma unroll
            for (int r = 0; r < 8; ++r) t8[r] = fmaxf(t8[r], fmaxf(s1[r], s1[r + 8]));
#pragma unroll
        for (int r = 0; r < 4; ++r) t8[r] = fmaxf(t8[r], t8[r + 4]);
        float tmax = fmaxf(fmaxf(t8[0], t8[1]), fmaxf(t8[2], t8[3]));
        tmax = fmaxf(tmax, __shfl_xor(tmax, 32, 64));

        if (!__all(tmax <= m_ + 8.f)) {                   // defer-max THR=8 (log2 units)
            float mn = fmaxf(m_, tmax);
            float alpha = exp2f(m_ - mn);
            m_ = mn;
            l_ *= alpha;
#pragma unroll
            for (int d0 = 0; d0 < 4; ++d0)
#pragma unroll
                for (int r = 0; r < 16; ++r) o[d0][r] *= alpha;
        }

        float p0[16], p1[16];
        float rs = 0.f;
#pragma unroll
        for (int r = 0; r < 16; ++r) { p0[r] = exp2f(s0[r] - m_); rs += p0[r]; }
        if (doh1)
#pragma unroll
            for (int r = 0; r < 16; ++r) { p1[r] = exp2f(s1[r] - m_); rs += p1[r]; }
        rs += __shfl_xor(rs, 32, 64);
        l_ += rs;

        // pack P -> bf16 B-frags: pfA (k0..k0+32), pfB (k0+32..k0+64)
        bf16x8 pfA[2], pfB[2];
        {
            unsigned int pk[8], po[8];
#pragma unroll
            for (int i = 0; i < 8; ++i) pk[i] = pk2bf(p0[2 * i], p0[2 * i + 1]);
#pragma unroll
            for (int i = 0; i < 8; ++i) po[i] = __shfl_xor(pk[i], 32, 64);
#pragma unroll
            for (int ks = 0; ks < 2; ++ks) {
                ui4 dw;
                dw[0] = hi ? po[ks * 4 + 2] : pk[ks * 4 + 0];
                dw[1] = hi ? po[ks * 4 + 3] : pk[ks * 4 + 1];
                dw[2] = hi ? pk[ks * 4 + 2] : po[ks * 4 + 0];
                dw[3] = hi ? pk[ks * 4 + 3] : po[ks * 4 + 1];
                pfA[ks] = __builtin_bit_cast(bf16x8, dw);
            }
        }
        if (doh1) {
            unsigned int pk[8], po[8];
#pragma unroll
            for (int i = 0; i < 8; ++i) pk[i] = pk2bf(p1[2 * i], p1[2 * i + 1]);
#pragma unroll
            for (int i = 0; i < 8; ++i) po[i] = __shfl_xor(pk[i], 32, 64);
#pragma unroll
            for (int ks = 0; ks < 2; ++ks) {
                ui4 dw;
                dw[0] = hi ? po[ks * 4 + 2] : pk[ks * 4 + 0];
                dw[1] = hi ? po[ks * 4 + 3] : pk[ks * 4 + 1];
                dw[2] = hi ? pk[ks * 4 + 2] : po[ks * 4 + 0];
                dw[3] = hi ? pk[ks * 4 + 3] : po[ks * 4 + 1];
                pfB[ks] = __builtin_bit_cast(bf16x8, dw);
            }
        }

        // V batch 2 (ks=2,3) issued before PV0 so it flies under the first MFMA cluster
        bf16x8 vf1[8];
        if (doh1) {
#pragma unroll
            for (int d0 = 0; d0 < 4; ++d0)
#pragma unroll
                for (int ks = 0; ks < 2; ++ks)
                    vf1[d0 * 2 + ks] = *(const bf16x8*)(Vh + (size_t)(d0 * 32 + q_l) * L + k0 + 32 + ks * 16 + hi * 8);
        }

        __builtin_amdgcn_s_setprio(1);
#pragma unroll
        for (int d0 = 0; d0 < 4; ++d0)
#pragma unroll
            for (int ks = 0; ks < 2; ++ks)
                o[d0] = __builtin_amdgcn_mfma_f32_32x32x16_bf16(vf0[d0 * 2 + ks], pfA[ks], o[d0], 0, 0, 0);
        if (doh1) {
#pragma unroll
            for (int d0 = 0; d0 < 4; ++d0)
#pragma unroll
                for (int ks = 0; ks < 2; ++ks)
                    o[d0] = __builtin_amdgcn_mfma_f32_32x32x16_bf16(vf1[d0 * 2 + ks], pfB[ks], o[d0], 0, 0, 0);
        }
        __builtin_amdgcn_s_setprio(0);
    }

    // ---- epilogue: lane owns q-row q0+q_l; d = d0*32 + (g*8 + hi*4 + 0..3) ----
    const float inv = 1.f / l_;
    const size_t rowbase = ((size_t)(b * 2048 + q0 + q_l)) * 2048 + h * 128;
#pragma unroll
    for (int d0 = 0; d0 < 4; ++d0)
#pragma unroll
        for (int g = 0; g < 4; ++g) {
            us4 v;
#pragma unroll
            for (int r = 0; r < 4; ++r) v[r] = f2bf(o[d0][g * 4 + r] * inv);
            *(us4*)(AO + rowbase + d0 * 32 + g * 8 + hi * 4) = v;
        }
}

// ---------------- launcher ----------------

extern "C" void kernel_launch(void* const* d_in, const int* in_sizes, int n_in,
                              void* d_out, int out_size, void* d_ws, size_t ws_size,
                              hipStream_t stream) {
    const float* x    = (const float*)d_in[0];   // [4,2048,2048]
    const float* Wqkv = (const float*)d_in[1];   // [2048,6144]
    const float* Wo   = (const float*)d_in[2];   // [2048,2048]
    float* out = (float*)d_out;                  // [4,2048,2048] fp32

    char* w = (char*)d_ws;
    ushort_t* xb   = (ushort_t*)(w);               // x bf16             33,554,432 B
    ushort_t* W1t  = (ushort_t*)(w + 33554432);    // Wqkv^T bf16        25,165,824 B
    ushort_t* Wot  = (ushort_t*)(w + 58720256);    // Wo^T bf16           8,388,608 B
    ushort_t* Qb   = (ushort_t*)(w + 67108864);    // Q roped [BH][L][D] 33,554,432 B
    ushort_t* Kbf  = (ushort_t*)(w + 100663296);   // K roped [BH][L][D] 33,554,432 B
    ushort_t* Vt   = (ushort_t*)(w + 134217728);   // V^T    [BH][D][L]  33,554,432 B
    ushort_t* AO   = (ushort_t*)(w + 167772160);   // attn out bf16      33,554,432 B
    float2*   rope = (float2*)(w + 201326592);     // [L][64] cos/sin     1,048,576 B

    cvt_bf16_kernel<<<16384, 256, 0, stream>>>((const float4*)x, (us4*)xb, 4194304);
    transpose_bf16<<<dim3(96, 32), 256, 0, stream>>>(Wqkv, W1t, 2048, 6144);
    transpose_bf16<<<dim3(32, 32), 256, 0, stream>>>(Wo, Wot, 2048, 2048);
    rope_table_kernel<<<512, 256, 0, stream>>>(rope);

    // qkv GEMM (proven 128^2) + fused rope/reshape epilogue
    gemm_bt<1><<<3072, 256, 0, stream>>>(xb, W1t, 8192, 6144, 2048,
                                         nullptr, Qb, Kbf, Vt, rope);
    // causal flash attention: KBLK=64, one wave per slice, longest-first
    attn_fwd<<<4096, 64, 0, stream>>>(Qb, Kbf, Vt, AO);
    // output projection (proven 128^2)
    gemm_bt<0><<<1024, 256, 0, stream>>>(AO, Wot, 8192, 2048, 2048,
                                         out, nullptr, nullptr, nullptr, nullptr);
}

// Round 11
// 618.863 us; speedup vs baseline: 1.6305x; 1.6305x over previous
//
#include <hip/hip_runtime.h>
#include <hip/hip_bf16.h>
#include <stdint.h>

typedef unsigned short ushort_t;
typedef __bf16 bf16x8 __attribute__((ext_vector_type(8)));
typedef float    f32x4 __attribute__((ext_vector_type(4)));
typedef float   f32x16 __attribute__((ext_vector_type(16)));
typedef unsigned short us4 __attribute__((ext_vector_type(4)));
typedef unsigned int ui4 __attribute__((ext_vector_type(4)));

#define QK_SCALE 0.12751744f   /* log2(e) / sqrt(128) : folded into Q so softmax uses exp2 */
#define NEG_BIG  -1e30f

__device__ __forceinline__ unsigned short f2bf(float f) {
    union { float f; unsigned int u; } v; v.f = f;
    unsigned int u = v.u;
    return (unsigned short)((u + 0x7FFFu + ((u >> 16) & 1u)) >> 16);  // RNE
}

// HW packed convert: dst.lo = bf16(a), dst.hi = bf16(b)
__device__ __forceinline__ unsigned int pk2bf(float a, float b) {
    unsigned int r;
    asm("v_cvt_pk_bf16_f32 %0, %1, %2" : "=v"(r) : "v"(a), "v"(b));
    return r;
}

// async global->LDS, 16B per lane. LDS dest is wave-uniform base + lane*16.
__device__ __forceinline__ void gload16(const void* g, void* l) {
    __builtin_amdgcn_global_load_lds(
        (__attribute__((address_space(1))) void*)(uintptr_t)g,
        (__attribute__((address_space(3))) void*)(uint32_t)(uintptr_t)l,
        16, 0, 0);
}

// ---------------- prep kernels ----------------

__global__ __launch_bounds__(256) void cvt_bf16_kernel(
    const float4* __restrict__ in, us4* __restrict__ out, int n4) {
    int i = blockIdx.x * 256 + threadIdx.x;
    if (i >= n4) return;
    float4 v = in[i];
    us4 o; o[0] = f2bf(v.x); o[1] = f2bf(v.y); o[2] = f2bf(v.z); o[3] = f2bf(v.w);
    out[i] = o;
}

// in [R][C] fp32  ->  out [C][R] bf16   (64x64 LDS tile transpose)
__global__ __launch_bounds__(256) void transpose_bf16(
    const float* __restrict__ in, ushort_t* __restrict__ out, int R, int C) {
    __shared__ float t[64][65];
    int c0 = blockIdx.x * 64, r0 = blockIdx.y * 64;
    int cc = threadIdx.x & 63, rr = threadIdx.x >> 6;
#pragma unroll
    for (int i = 0; i < 16; ++i) {
        int r = i * 4 + rr;
        t[r][cc] = in[(size_t)(r0 + r) * C + c0 + cc];
    }
    __syncthreads();
#pragma unroll
    for (int i = 0; i < 16; ++i) {
        int r = i * 4 + rr;
        out[(size_t)(c0 + r) * R + r0 + cc] = f2bf(t[cc][r]);
    }
}

// rope table: [L][64] of (cos, sin)
__global__ __launch_bounds__(256) void rope_table_kernel(float2* __restrict__ rope) {
    int i = blockIdx.x * 256 + threadIdx.x;     // L*64 = 131072 exactly
    int l = i >> 6, j = i & 63;
    float inv = exp2f((float)j * -0.20762050593046f);  // 10000^(-j/64)
    float f = (float)l * inv;
    rope[i] = make_float2(cosf(f), sinf(f));
}

// ---------------- GEMM (proven 128^2):  C = A * Bt^T  (bf16 in, fp32 acc) ----------------

template <int EPI>
__global__ __launch_bounds__(256, 2)
void gemm_bt(const ushort_t* __restrict__ A, const ushort_t* __restrict__ Bt,
             int M, int N, int K,
             float* __restrict__ C,
             ushort_t* __restrict__ Qb, ushort_t* __restrict__ Kb,
             ushort_t* __restrict__ Vt, const float2* __restrict__ rope) {
    constexpr int MI = (EPI == 1) ? 2 : 4;
    constexpr int NI = (EPI == 1) ? 8 : 4;

    __shared__ __attribute__((aligned(16))) ushort_t ldsA[128 * 64];
    __shared__ __attribute__((aligned(16))) ushort_t ldsB[128 * 64];
    char* ldsAc = (char*)ldsA;
    char* ldsBc = (char*)ldsB;

    const int tid  = threadIdx.x;
    const int lane = tid & 63, wid = tid >> 6;
    const int lr = lane & 15, lg = lane >> 4;

    const int nbn = N >> 7;
    const int nwg = gridDim.x;
    const int bid = blockIdx.x;
    const int wg  = (bid & 7) * (nwg >> 3) + (bid >> 3);   // XCD-contiguous chunks
    const int bm  = wg / nbn, bn = wg % nbn;

    const int arow0 = (EPI == 1) ? wid * 32 : (wid >> 1) * 64;
    const int bcol0 = (EPI == 1) ? 0        : (wid & 1) * 64;

    const int colb = ((tid & 7) << 4) ^ (((tid >> 3) & 7) << 4);
    const int rowi = tid >> 3;                       // 0..31
    const char* Ap = (const char*)A + ((size_t)(bm * 128 + rowi) * K) * 2 + colb;
    const char* Bp = (const char*)Bt + ((size_t)(bn * 128 + rowi) * K) * 2 + colb;
    const size_t rstr = (size_t)32 * K * 2;
    char* ldA = ldsAc + wid * 1024;
    char* ldB = ldsBc + wid * 1024;

    f32x4 acc[MI][NI];
#pragma unroll
    for (int i = 0; i < MI; ++i)
#pragma unroll
        for (int j = 0; j < NI; ++j) acc[i][j] = (f32x4){0.f, 0.f, 0.f, 0.f};

    for (int k0 = 0; k0 < K; k0 += 64) {
#pragma unroll
        for (int r = 0; r < 4; ++r) {
            gload16(Ap + r * rstr + (size_t)k0 * 2, ldA + r * 4096);
            gload16(Bp + r * rstr + (size_t)k0 * 2, ldB + r * 4096);
        }
        __syncthreads();
#pragma unroll
        for (int kk = 0; kk < 2; ++kk) {
            bf16x8 af[MI], bfv[NI];
#pragma unroll
            for (int mi = 0; mi < MI; ++mi) {
                int row = arow0 + mi * 16 + lr;
                int off = (row << 7) + kk * 64 + lg * 16;
                off ^= (row & 7) << 4;
                af[mi] = *(const bf16x8*)(ldsAc + off);
            }
#pragma unroll
            for (int ni = 0; ni < NI; ++ni) {
                int row = bcol0 + ni * 16 + lr;
                int off = (row << 7) + kk * 64 + lg * 16;
                off ^= (row & 7) << 4;
                bfv[ni] = *(const bf16x8*)(ldsBc + off);
            }
#pragma unroll
            for (int mi = 0; mi < MI; ++mi)
#pragma unroll
                for (int ni = 0; ni < NI; ++ni)
                    acc[mi][ni] = __builtin_amdgcn_mfma_f32_16x16x32_bf16(
                        af[mi], bfv[ni], acc[mi][ni], 0, 0, 0);
        }
        __syncthreads();
    }

    if constexpr (EPI == 0) {
#pragma unroll
        for (int mi = 0; mi < MI; ++mi) {
            int gr0 = bm * 128 + arow0 + mi * 16 + lg * 4;
#pragma unroll
            for (int ni = 0; ni < NI; ++ni) {
                int gc = bn * 128 + bcol0 + ni * 16 + lr;
#pragma unroll
                for (int r = 0; r < 4; ++r)
                    C[(size_t)(gr0 + r) * N + gc] = acc[mi][ni][r];
            }
        }
    } else {
        const int which = bn >> 4, h = bn & 15;
#pragma unroll
        for (int mi = 0; mi < MI; ++mi) {
            int gr0 = bm * 128 + arow0 + mi * 16 + lg * 4;   // = b*L + l0 (4 consecutive l)
            int b = gr0 >> 11, l0 = gr0 & 2047;
            if (which == 2) {                                 // V -> [BH][D][L] (transposed)
#pragma unroll
                for (int ni = 0; ni < NI; ++ni) {
                    int d = ni * 16 + lr;
                    us4 pk;
#pragma unroll
                    for (int r = 0; r < 4; ++r) pk[r] = f2bf(acc[mi][ni][r]);
                    *(us4*)(Vt + ((size_t)(b * 16 + h) * 128 + d) * 2048 + l0) = pk;
                }
            } else {                                          // Q/K: rope, -> [BH][L][D]
                ushort_t* dst = (which == 0) ? Qb : Kb;
                const float sc = (which == 0) ? QK_SCALE : 1.0f;
#pragma unroll
                for (int ni = 0; ni < 4; ++ni) {
                    int j = ni * 16 + lr;                     // d < 64 ; pair at d+64 = frag ni+4
#pragma unroll
                    for (int r = 0; r < 4; ++r) {
                        float2 cs = rope[(size_t)(l0 + r) * 64 + j];
                        float x1 = acc[mi][ni][r], x2 = acc[mi][ni + 4][r];
                        size_t base = ((size_t)(b * 16 + h) * 2048 + (l0 + r)) * 128;
                        dst[base + j]      = f2bf((x1 * cs.x - x2 * cs.y) * sc);
                        dst[base + j + 64] = f2bf((x2 * cs.x + x1 * cs.y) * sc);
                    }
                }
            }
        }
    }
}

// ---------------- causal flash attention (R6 dataflow + head-pair L2 phasing) ----------------
// Q,K: [BH][L][128] bf16 (Q pre-scaled); V^T: [BH][128][L] bf16; AO: [B][L][H*128] bf16.
// R6 arithmetic verified at 266us (VGPR 100). New: per XCD, process 2 heads at a time
// (K+V working set 2MB <= 4MB L2 instead of 8MB -> K/V stream from L2 not L3). 4 phases
// of 128 blocks per XCD, dispatched in bid order; longest-slice-first within each phase.

__global__ __attribute__((amdgpu_flat_work_group_size(64, 64), amdgpu_waves_per_eu(2, 2)))
void attn_fwd(const ushort_t* __restrict__ Qb, const ushort_t* __restrict__ Kb,
              const ushort_t* __restrict__ Vt, ushort_t* __restrict__ AO) {
    constexpr int L = 2048;
    const int lane = threadIdx.x;
    const int q_l  = lane & 31;
    const int hi   = lane >> 5;

    // 4096 blocks. xcd = bid&7; idx 0..511 per xcd; phase = idx>>7 (2 heads per phase);
    // within phase: rr = (idx&127)>>1 -> sl = 63-rr (longest first), hl2 = idx&1.
    const int bid  = blockIdx.x;
    const int xcd  = bid & 7;
    const int idx  = bid >> 3;
    const int ph   = idx >> 7;                  // 0..3
    const int wp   = idx & 127;
    const int hl2  = wp & 1;
    const int rr   = wp >> 1;                   // 0..63
    const int head = xcd * 8 + ph * 2 + hl2;
    const int sl   = 63 - rr;
    const int q0   = sl * 32;

    const ushort_t* Qh = Qb + (size_t)head * L * 128;
    const ushort_t* Kh = Kb + (size_t)head * L * 128;
    const ushort_t* Vh = Vt + (size_t)head * 128 * L;
    const int b = head >> 4, h = head & 15;

    // Q^T B-frags hoisted: lane holds Q[q0+q_l][sb*16 + hi*8 + 0..7]
    bf16x8 qf[8];
#pragma unroll
    for (int sb = 0; sb < 8; ++sb)
        qf[sb] = *(const bf16x8*)(Qh + (size_t)(q0 + q_l) * 128 + sb * 16 + hi * 8);

    f32x16 o[4];
#pragma unroll
    for (int d0 = 0; d0 < 4; ++d0) o[d0] = (f32x16)(0.f);
    float m_ = -__builtin_inff(), l_ = 0.f;

    // K(0) preload
    bf16x8 kf[8];
#pragma unroll
    for (int sb = 0; sb < 8; ++sb)
        kf[sb] = *(const bf16x8*)(Kh + (size_t)q_l * 128 + sb * 16 + hi * 8);

    const int ntile = sl + 1;
    for (int t = 0; t < ntile; ++t) {
        const int k0 = t * 32;

        // ---- V loads for THIS tile issued first (consumed after softmax) ----
        bf16x8 vf[8];
#pragma unroll
        for (int d0 = 0; d0 < 4; ++d0)
#pragma unroll
            for (int ks = 0; ks < 2; ++ks)
                vf[d0 * 2 + ks] = *(const bf16x8*)(Vh + (size_t)(d0 * 32 + q_l) * L + k0 + ks * 16 + hi * 8);

        // ---- S^T = K * Q^T : two accumulator chains (kf already in registers) ----
        f32x16 sa = (f32x16)(0.f), sb2 = (f32x16)(0.f);
#pragma unroll
        for (int sb = 0; sb < 8; sb += 2) {
            sa  = __builtin_amdgcn_mfma_f32_32x32x16_bf16(kf[sb],     qf[sb],     sa,  0, 0, 0);
            sb2 = __builtin_amdgcn_mfma_f32_32x32x16_bf16(kf[sb + 1], qf[sb + 1], sb2, 0, 0, 0);
        }
        f32x16 s = sa + sb2;

        // ---- K(t+1) prefetch: latency hides under softmax + PV of tile t ----
        if (t + 1 < ntile) {
            const int kn = k0 + 32;
#pragma unroll
            for (int sb = 0; sb < 8; ++sb)
                kf[sb] = *(const bf16x8*)(Kh + (size_t)(kn + q_l) * 128 + sb * 16 + hi * 8);
        }

        // causal mask on the diagonal tile: k = k0 + crow(reg,hi), q = q0 + q_l, k0==q0
        if (t == ntile - 1) {
#pragma unroll
            for (int r = 0; r < 16; ++r) {
                int kk = (r & 3) + 8 * (r >> 2) + 4 * hi;
                if (kk > q_l) s[r] = NEG_BIG;
            }
        }

        // ---- in-register online softmax (lane owns q-row q0+q_l) ----
        float t8[8];
#pragma unroll
        for (int r = 0; r < 8; ++r) t8[r] = fmaxf(s[r], s[r + 8]);
#pragma unroll
        for (int r = 0; r < 4; ++r) t8[r] = fmaxf(t8[r], t8[r + 4]);
        float tmax = fmaxf(fmaxf(t8[0], t8[1]), fmaxf(t8[2], t8[3]));
        tmax = fmaxf(tmax, __shfl_xor(tmax, 32, 64));     // full 32-k row max

        if (!__all(tmax <= m_ + 8.f)) {                   // defer-max THR=8 (log2 units)
            float mn = fmaxf(m_, tmax);
            float alpha = exp2f(m_ - mn);
            m_ = mn;
            l_ *= alpha;
#pragma unroll
            for (int d0 = 0; d0 < 4; ++d0)
#pragma unroll
                for (int r = 0; r < 16; ++r) o[d0][r] *= alpha;
        }

        float p[16];
        float rs = 0.f;
#pragma unroll
        for (int r = 0; r < 16; ++r) { p[r] = exp2f(s[r] - m_); rs += p[r]; }
        rs += __shfl_xor(rs, 32, 64);
        l_ += rs;

        // ---- pack P -> bf16 pairs (HW cvt_pk); assemble P^T B-frags via partner exchange ----
        unsigned int pk[8];
#pragma unroll
        for (int i = 0; i < 8; ++i) pk[i] = pk2bf(p[2 * i], p[2 * i + 1]);
        unsigned int po[8];
#pragma unroll
        for (int i = 0; i < 8; ++i) po[i] = __shfl_xor(pk[i], 32, 64);

        bf16x8 pf[2];
#pragma unroll
        for (int ks = 0; ks < 2; ++ks) {
            ui4 dw;
            dw[0] = hi ? po[ks * 4 + 2] : pk[ks * 4 + 0];
            dw[1] = hi ? po[ks * 4 + 3] : pk[ks * 4 + 1];
            dw[2] = hi ? pk[ks * 4 + 2] : po[ks * 4 + 0];
            dw[3] = hi ? pk[ks * 4 + 3] : po[ks * 4 + 1];
            pf[ks] = __builtin_bit_cast(bf16x8, dw);
        }

        // ---- O^T += V^T * P^T : vf long in flight; MFMAs back-to-back ----
#pragma unroll
        for (int d0 = 0; d0 < 4; ++d0)
#pragma unroll
            for (int ks = 0; ks < 2; ++ks)
                o[d0] = __builtin_amdgcn_mfma_f32_32x32x16_bf16(vf[d0 * 2 + ks], pf[ks], o[d0], 0, 0, 0);
    }

    // ---- epilogue: lane owns q-row q0+q_l entirely; d = d0*32 + (g*8 + hi*4 + 0..3) ----
    const float inv = 1.f / l_;
    const size_t rowbase = ((size_t)(b * 2048 + q0 + q_l)) * 2048 + h * 128;
#pragma unroll
    for (int d0 = 0; d0 < 4; ++d0)
#pragma unroll
        for (int g = 0; g < 4; ++g) {
            us4 v;
#pragma unroll
            for (int r = 0; r < 4; ++r) v[r] = f2bf(o[d0][g * 4 + r] * inv);
            *(us4*)(AO + rowbase + d0 * 32 + g * 8 + hi * 4) = v;
        }
}

// ---------------- launcher ----------------

extern "C" void kernel_launch(void* const* d_in, const int* in_sizes, int n_in,
                              void* d_out, int out_size, void* d_ws, size_t ws_size,
                              hipStream_t stream) {
    const float* x    = (const float*)d_in[0];   // [4,2048,2048]
    const float* Wqkv = (const float*)d_in[1];   // [2048,6144]
    const float* Wo   = (const float*)d_in[2];   // [2048,2048]
    float* out = (float*)d_out;                  // [4,2048,2048] fp32

    char* w = (char*)d_ws;
    ushort_t* xb   = (ushort_t*)(w);               // x bf16             33,554,432 B
    ushort_t* W1t  = (ushort_t*)(w + 33554432);    // Wqkv^T bf16        25,165,824 B
    ushort_t* Wot  = (ushort_t*)(w + 58720256);    // Wo^T bf16           8,388,608 B
    ushort_t* Qb   = (ushort_t*)(w + 67108864);    // Q roped [BH][L][D] 33,554,432 B
    ushort_t* Kbf  = (ushort_t*)(w + 100663296);   // K roped [BH][L][D] 33,554,432 B
    ushort_t* Vt   = (ushort_t*)(w + 134217728);   // V^T    [BH][D][L]  33,554,432 B
    ushort_t* AO   = (ushort_t*)(w + 167772160);   // attn out bf16      33,554,432 B
    float2*   rope = (float2*)(w + 201326592);     // [L][64] cos/sin     1,048,576 B

    cvt_bf16_kernel<<<16384, 256, 0, stream>>>((const float4*)x, (us4*)xb, 4194304);
    transpose_bf16<<<dim3(96, 32), 256, 0, stream>>>(Wqkv, W1t, 2048, 6144);
    transpose_bf16<<<dim3(32, 32), 256, 0, stream>>>(Wo, Wot, 2048, 2048);
    rope_table_kernel<<<512, 256, 0, stream>>>(rope);

    // qkv GEMM (proven 128^2) + fused rope/reshape epilogue
    gemm_bt<1><<<3072, 256, 0, stream>>>(xb, W1t, 8192, 6144, 2048,
                                         nullptr, Qb, Kbf, Vt, rope);
    // causal flash attention: head-pair phased for L2 residency
    attn_fwd<<<4096, 64, 0, stream>>>(Qb, Kbf, Vt, AO);
    // output projection (proven 128^2)
    gemm_bt<0><<<1024, 256, 0, stream>>>(AO, Wot, 8192, 2048, 2048,
                                         out, nullptr, nullptr, nullptr, nullptr);
}

// Round 12
// 610.913 us; speedup vs baseline: 1.6517x; 1.0130x over previous
//
#include <hip/hip_runtime.h>
#include <hip/hip_bf16.h>
#include <stdint.h>

typedef unsigned short ushort_t;
typedef __bf16 bf16x8 __attribute__((ext_vector_type(8)));
typedef float    f32x4 __attribute__((ext_vector_type(4)));
typedef float   f32x16 __attribute__((ext_vector_type(16)));
typedef unsigned short us4 __attribute__((ext_vector_type(4)));
typedef unsigned int ui4 __attribute__((ext_vector_type(4)));

#define QK_SCALE 0.12751744f   /* log2(e) / sqrt(128) : folded into Q so softmax uses exp2 */
#define NEG_BIG  -1e30f

__device__ __forceinline__ unsigned short f2bf(float f) {
    union { float f; unsigned int u; } v; v.f = f;
    unsigned int u = v.u;
    return (unsigned short)((u + 0x7FFFu + ((u >> 16) & 1u)) >> 16);  // RNE
}

// HW packed convert: dst.lo = bf16(a), dst.hi = bf16(b)
__device__ __forceinline__ unsigned int pk2bf(float a, float b) {
    unsigned int r;
    asm("v_cvt_pk_bf16_f32 %0, %1, %2" : "=v"(r) : "v"(a), "v"(b));
    return r;
}

// pinned 16B global load: volatile asm cannot be sunk by the scheduler.
// Completion is guaranteed only after an explicit s_waitcnt vmcnt(N).
__device__ __forceinline__ ui4 gld4(const void* addr) {
    ui4 r;
    asm volatile("global_load_dwordx4 %0, %1, off" : "=&v"(r) : "v"(addr));
    return r;
}

// async global->LDS, 16B per lane. LDS dest is wave-uniform base + lane*16.
__device__ __forceinline__ void gload16(const void* g, void* l) {
    __builtin_amdgcn_global_load_lds(
        (__attribute__((address_space(1))) void*)(uintptr_t)g,
        (__attribute__((address_space(3))) void*)(uint32_t)(uintptr_t)l,
        16, 0, 0);
}

// ---------------- prep kernels ----------------

__global__ __launch_bounds__(256) void cvt_bf16_kernel(
    const float4* __restrict__ in, us4* __restrict__ out, int n4) {
    int i = blockIdx.x * 256 + threadIdx.x;
    if (i >= n4) return;
    float4 v = in[i];
    us4 o; o[0] = f2bf(v.x); o[1] = f2bf(v.y); o[2] = f2bf(v.z); o[3] = f2bf(v.w);
    out[i] = o;
}

// in [R][C] fp32  ->  out [C][R] bf16   (64x64 LDS tile transpose)
__global__ __launch_bounds__(256) void transpose_bf16(
    const float* __restrict__ in, ushort_t* __restrict__ out, int R, int C) {
    __shared__ float t[64][65];
    int c0 = blockIdx.x * 64, r0 = blockIdx.y * 64;
    int cc = threadIdx.x & 63, rr = threadIdx.x >> 6;
#pragma unroll
    for (int i = 0; i < 16; ++i) {
        int r = i * 4 + rr;
        t[r][cc] = in[(size_t)(r0 + r) * C + c0 + cc];
    }
    __syncthreads();
#pragma unroll
    for (int i = 0; i < 16; ++i) {
        int r = i * 4 + rr;
        out[(size_t)(c0 + r) * R + r0 + cc] = f2bf(t[cc][r]);
    }
}

// rope table: [L][64] of (cos, sin)
__global__ __launch_bounds__(256) void rope_table_kernel(float2* __restrict__ rope) {
    int i = blockIdx.x * 256 + threadIdx.x;     // L*64 = 131072 exactly
    int l = i >> 6, j = i & 63;
    float inv = exp2f((float)j * -0.20762050593046f);  // 10000^(-j/64)
    float f = (float)l * inv;
    rope[i] = make_float2(cosf(f), sinf(f));
}

// ---------------- GEMM (proven 128^2):  C = A * Bt^T  (bf16 in, fp32 acc) ----------------

template <int EPI>
__global__ __launch_bounds__(256, 2)
void gemm_bt(const ushort_t* __restrict__ A, const ushort_t* __restrict__ Bt,
             int M, int N, int K,
             float* __restrict__ C,
             ushort_t* __restrict__ Qb, ushort_t* __restrict__ Kb,
             ushort_t* __restrict__ Vt, const float2* __restrict__ rope) {
    constexpr int MI = (EPI == 1) ? 2 : 4;
    constexpr int NI = (EPI == 1) ? 8 : 4;

    __shared__ __attribute__((aligned(16))) ushort_t ldsA[128 * 64];
    __shared__ __attribute__((aligned(16))) ushort_t ldsB[128 * 64];
    char* ldsAc = (char*)ldsA;
    char* ldsBc = (char*)ldsB;

    const int tid  = threadIdx.x;
    const int lane = tid & 63, wid = tid >> 6;
    const int lr = lane & 15, lg = lane >> 4;

    const int nbn = N >> 7;
    const int nwg = gridDim.x;
    const int bid = blockIdx.x;
    const int wg  = (bid & 7) * (nwg >> 3) + (bid >> 3);   // XCD-contiguous chunks
    const int bm  = wg / nbn, bn = wg % nbn;

    const int arow0 = (EPI == 1) ? wid * 32 : (wid >> 1) * 64;
    const int bcol0 = (EPI == 1) ? 0        : (wid & 1) * 64;

    const int colb = ((tid & 7) << 4) ^ (((tid >> 3) & 7) << 4);
    const int rowi = tid >> 3;                       // 0..31
    const char* Ap = (const char*)A + ((size_t)(bm * 128 + rowi) * K) * 2 + colb;
    const char* Bp = (const char*)Bt + ((size_t)(bn * 128 + rowi) * K) * 2 + colb;
    const size_t rstr = (size_t)32 * K * 2;
    char* ldA = ldsAc + wid * 1024;
    char* ldB = ldsBc + wid * 1024;

    f32x4 acc[MI][NI];
#pragma unroll
    for (int i = 0; i < MI; ++i)
#pragma unroll
        for (int j = 0; j < NI; ++j) acc[i][j] = (f32x4){0.f, 0.f, 0.f, 0.f};

    for (int k0 = 0; k0 < K; k0 += 64) {
#pragma unroll
        for (int r = 0; r < 4; ++r) {
            gload16(Ap + r * rstr + (size_t)k0 * 2, ldA + r * 4096);
            gload16(Bp + r * rstr + (size_t)k0 * 2, ldB + r * 4096);
        }
        __syncthreads();
#pragma unroll
        for (int kk = 0; kk < 2; ++kk) {
            bf16x8 af[MI], bfv[NI];
#pragma unroll
            for (int mi = 0; mi < MI; ++mi) {
                int row = arow0 + mi * 16 + lr;
                int off = (row << 7) + kk * 64 + lg * 16;
                off ^= (row & 7) << 4;
                af[mi] = *(const bf16x8*)(ldsAc + off);
            }
#pragma unroll
            for (int ni = 0; ni < NI; ++ni) {
                int row = bcol0 + ni * 16 + lr;
                int off = (row << 7) + kk * 64 + lg * 16;
                off ^= (row & 7) << 4;
                bfv[ni] = *(const bf16x8*)(ldsBc + off);
            }
#pragma unroll
            for (int mi = 0; mi < MI; ++mi)
#pragma unroll
                for (int ni = 0; ni < NI; ++ni)
                    acc[mi][ni] = __builtin_amdgcn_mfma_f32_16x16x32_bf16(
                        af[mi], bfv[ni], acc[mi][ni], 0, 0, 0);
        }
        __syncthreads();
    }

    if constexpr (EPI == 0) {
#pragma unroll
        for (int mi = 0; mi < MI; ++mi) {
            int gr0 = bm * 128 + arow0 + mi * 16 + lg * 4;
#pragma unroll
            for (int ni = 0; ni < NI; ++ni) {
                int gc = bn * 128 + bcol0 + ni * 16 + lr;
#pragma unroll
                for (int r = 0; r < 4; ++r)
                    C[(size_t)(gr0 + r) * N + gc] = acc[mi][ni][r];
            }
        }
    } else {
        const int which = bn >> 4, h = bn & 15;
#pragma unroll
        for (int mi = 0; mi < MI; ++mi) {
            int gr0 = bm * 128 + arow0 + mi * 16 + lg * 4;   // = b*L + l0 (4 consecutive l)
            int b = gr0 >> 11, l0 = gr0 & 2047;
            if (which == 2) {                                 // V -> [BH][D][L] (transposed)
#pragma unroll
                for (int ni = 0; ni < NI; ++ni) {
                    int d = ni * 16 + lr;
                    us4 pk;
#pragma unroll
                    for (int r = 0; r < 4; ++r) pk[r] = f2bf(acc[mi][ni][r]);
                    *(us4*)(Vt + ((size_t)(b * 16 + h) * 128 + d) * 2048 + l0) = pk;
                }
            } else {                                          // Q/K: rope, -> [BH][L][D]
                ushort_t* dst = (which == 0) ? Qb : Kb;
                const float sc = (which == 0) ? QK_SCALE : 1.0f;
#pragma unroll
                for (int ni = 0; ni < 4; ++ni) {
                    int j = ni * 16 + lr;                     // d < 64 ; pair at d+64 = frag ni+4
#pragma unroll
                    for (int r = 0; r < 4; ++r) {
                        float2 cs = rope[(size_t)(l0 + r) * 64 + j];
                        float x1 = acc[mi][ni][r], x2 = acc[mi][ni + 4][r];
                        size_t base = ((size_t)(b * 16 + h) * 2048 + (l0 + r)) * 128;
                        dst[base + j]      = f2bf((x1 * cs.x - x2 * cs.y) * sc);
                        dst[base + j + 64] = f2bf((x2 * cs.x + x1 * cs.y) * sc);
                    }
                }
            }
        }
    }
}

// ---------------- causal flash attention (R6 dataflow + pinned-asm K/V loads) ----------------
// Q,K: [BH][L][128] bf16 (Q pre-scaled); V^T: [BH][128][L] bf16; AO: [B][L][H*128] bf16.
// R6's per-wave dataflow, but K/V fragments loaded via volatile-asm global_load_dwordx4 so
// the scheduler CANNOT sink them to their uses (R5/R6/R11 post-mortem: compiler sank the
// C++ "prefetch" loads to fit 100 VGPRs -> ~8 serialized L2 round-trips per tile).
// Per tile: issue K(8) then V(8); vmcnt(8)+sched_barrier before S (K ready, V flying);
// V drains under softmax; vmcnt(0)+sched_barrier before PV. No other VMEM in the loop,
// so the counts are exact (in-order completion).

__global__ __attribute__((amdgpu_flat_work_group_size(64, 64), amdgpu_waves_per_eu(2, 2)))
void attn_fwd(const ushort_t* __restrict__ Qb, const ushort_t* __restrict__ Kb,
              const ushort_t* __restrict__ Vt, ushort_t* __restrict__ AO) {
    constexpr int L = 2048;
    const int lane = threadIdx.x;
    const int q_l  = lane & 31;
    const int hi   = lane >> 5;

    // 4096 blocks: xcd = bid&7, heads 0..7 per xcd, rank 0..63 -> sl = 63-rank (longest first)
    const int bid  = blockIdx.x;
    const int j    = bid >> 3;
    const int hl   = j & 7;
    const int rank = j >> 3;
    const int head = (bid & 7) * 8 + hl;
    const int sl   = 63 - rank;
    const int q0   = sl * 32;

    const ushort_t* Qh = Qb + (size_t)head * L * 128;
    const ushort_t* Kh = Kb + (size_t)head * L * 128;
    const ushort_t* Vh = Vt + (size_t)head * 128 * L;
    const int b = head >> 4, h = head & 15;

    // Q^T B-frags hoisted (plain loads; compiler drains them before first use)
    bf16x8 qf[8];
#pragma unroll
    for (int sb = 0; sb < 8; ++sb)
        qf[sb] = *(const bf16x8*)(Qh + (size_t)(q0 + q_l) * 128 + sb * 16 + hi * 8);

    f32x16 o[4];
#pragma unroll
    for (int d0 = 0; d0 < 4; ++d0) o[d0] = (f32x16)(0.f);
    float m_ = -__builtin_inff(), l_ = 0.f;

    const int ntile = sl + 1;
    for (int t = 0; t < ntile; ++t) {
        const int k0 = t * 32;

        // ---- pinned loads: K first (waited at vmcnt(8)), then V (drains under softmax) ----
        ui4 kfu[8], vfu[8];
#pragma unroll
        for (int sb = 0; sb < 8; ++sb)
            kfu[sb] = gld4(Kh + (size_t)(k0 + q_l) * 128 + sb * 16 + hi * 8);
#pragma unroll
        for (int d0 = 0; d0 < 4; ++d0)
#pragma unroll
            for (int ks = 0; ks < 2; ++ks)
                vfu[d0 * 2 + ks] = gld4(Vh + (size_t)(d0 * 32 + q_l) * L + k0 + ks * 16 + hi * 8);

        asm volatile("s_waitcnt vmcnt(8)" ::: "memory");   // K(8) done; V(8) in flight
        __builtin_amdgcn_sched_barrier(0);

        // ---- S^T = K * Q^T : two accumulator chains ----
        f32x16 sa = (f32x16)(0.f), sb2 = (f32x16)(0.f);
#pragma unroll
        for (int sb = 0; sb < 8; sb += 2) {
            sa  = __builtin_amdgcn_mfma_f32_32x32x16_bf16(__builtin_bit_cast(bf16x8, kfu[sb]),     qf[sb],     sa,  0, 0, 0);
            sb2 = __builtin_amdgcn_mfma_f32_32x32x16_bf16(__builtin_bit_cast(bf16x8, kfu[sb + 1]), qf[sb + 1], sb2, 0, 0, 0);
        }
        f32x16 s = sa + sb2;

        // causal mask on the diagonal tile: k = k0 + crow(reg,hi), q = q0 + q_l, k0==q0
        if (t == ntile - 1) {
#pragma unroll
            for (int r = 0; r < 16; ++r) {
                int kk = (r & 3) + 8 * (r >> 2) + 4 * hi;
                if (kk > q_l) s[r] = NEG_BIG;
            }
        }

        // ---- in-register online softmax (lane owns q-row q0+q_l) ----
        float t8[8];
#pragma unroll
        for (int r = 0; r < 8; ++r) t8[r] = fmaxf(s[r], s[r + 8]);
#pragma unroll
        for (int r = 0; r < 4; ++r) t8[r] = fmaxf(t8[r], t8[r + 4]);
        float tmax = fmaxf(fmaxf(t8[0], t8[1]), fmaxf(t8[2], t8[3]));
        tmax = fmaxf(tmax, __shfl_xor(tmax, 32, 64));     // full 32-k row max

        if (!__all(tmax <= m_ + 8.f)) {                   // defer-max THR=8 (log2 units)
            float mn = fmaxf(m_, tmax);
            float alpha = exp2f(m_ - mn);
            m_ = mn;
            l_ *= alpha;
#pragma unroll
            for (int d0 = 0; d0 < 4; ++d0)
#pragma unroll
                for (int r = 0; r < 16; ++r) o[d0][r] *= alpha;
        }

        float p[16];
        float rs = 0.f;
#pragma unroll
        for (int r = 0; r < 16; ++r) { p[r] = exp2f(s[r] - m_); rs += p[r]; }
        rs += __shfl_xor(rs, 32, 64);
        l_ += rs;

        // ---- pack P -> bf16 pairs (HW cvt_pk); assemble P^T B-frags via partner exchange ----
        unsigned int pk[8];
#pragma unroll
        for (int i = 0; i < 8; ++i) pk[i] = pk2bf(p[2 * i], p[2 * i + 1]);
        unsigned int po[8];
#pragma unroll
        for (int i = 0; i < 8; ++i) po[i] = __shfl_xor(pk[i], 32, 64);

        bf16x8 pf[2];
#pragma unroll
        for (int ks = 0; ks < 2; ++ks) {
            ui4 dw;
            dw[0] = hi ? po[ks * 4 + 2] : pk[ks * 4 + 0];
            dw[1] = hi ? po[ks * 4 + 3] : pk[ks * 4 + 1];
            dw[2] = hi ? pk[ks * 4 + 2] : po[ks * 4 + 0];
            dw[3] = hi ? pk[ks * 4 + 3] : po[ks * 4 + 1];
            pf[ks] = __builtin_bit_cast(bf16x8, dw);
        }

        asm volatile("s_waitcnt vmcnt(0)" ::: "memory");   // V(8) done
        __builtin_amdgcn_sched_barrier(0);

        // ---- O^T += V^T * P^T ----
#pragma unroll
        for (int d0 = 0; d0 < 4; ++d0)
#pragma unroll
            for (int ks = 0; ks < 2; ++ks)
                o[d0] = __builtin_amdgcn_mfma_f32_32x32x16_bf16(
                    __builtin_bit_cast(bf16x8, vfu[d0 * 2 + ks]), pf[ks], o[d0], 0, 0, 0);
    }

    // ---- epilogue: lane owns q-row q0+q_l entirely; d = d0*32 + (g*8 + hi*4 + 0..3) ----
    const float inv = 1.f / l_;
    const size_t rowbase = ((size_t)(b * 2048 + q0 + q_l)) * 2048 + h * 128;
#pragma unroll
    for (int d0 = 0; d0 < 4; ++d0)
#pragma unroll
        for (int g = 0; g < 4; ++g) {
            us4 v;
#pragma unroll
            for (int r = 0; r < 4; ++r) v[r] = f2bf(o[d0][g * 4 + r] * inv);
            *(us4*)(AO + rowbase + d0 * 32 + g * 8 + hi * 4) = v;
        }
}

// ---------------- launcher ----------------

extern "C" void kernel_launch(void* const* d_in, const int* in_sizes, int n_in,
                              void* d_out, int out_size, void* d_ws, size_t ws_size,
                              hipStream_t stream) {
    const float* x    = (const float*)d_in[0];   // [4,2048,2048]
    const float* Wqkv = (const float*)d_in[1];   // [2048,6144]
    const float* Wo   = (const float*)d_in[2];   // [2048,2048]
    float* out = (float*)d_out;                  // [4,2048,2048] fp32

    char* w = (char*)d_ws;
    ushort_t* xb   = (ushort_t*)(w);               // x bf16             33,554,432 B
    ushort_t* W1t  = (ushort_t*)(w + 33554432);    // Wqkv^T bf16        25,165,824 B
    ushort_t* Wot  = (ushort_t*)(w + 58720256);    // Wo^T bf16           8,388,608 B
    ushort_t* Qb   = (ushort_t*)(w + 67108864);    // Q roped [BH][L][D] 33,554,432 B
    ushort_t* Kbf  = (ushort_t*)(w + 100663296);   // K roped [BH][L][D] 33,554,432 B
    ushort_t* Vt   = (ushort_t*)(w + 134217728);   // V^T    [BH][D][L]  33,554,432 B
    ushort_t* AO   = (ushort_t*)(w + 167772160);   // attn out bf16      33,554,432 B
    float2*   rope = (float2*)(w + 201326592);     // [L][64] cos/sin     1,048,576 B

    cvt_bf16_kernel<<<16384, 256, 0, stream>>>((const float4*)x, (us4*)xb, 4194304);
    transpose_bf16<<<dim3(96, 32), 256, 0, stream>>>(Wqkv, W1t, 2048, 6144);
    transpose_bf16<<<dim3(32, 32), 256, 0, stream>>>(Wo, Wot, 2048, 2048);
    rope_table_kernel<<<512, 256, 0, stream>>>(rope);

    // qkv GEMM (proven 128^2) + fused rope/reshape epilogue
    gemm_bt<1><<<3072, 256, 0, stream>>>(xb, W1t, 8192, 6144, 2048,
                                         nullptr, Qb, Kbf, Vt, rope);
    // causal flash attention: pinned-asm K/V prefetch, counted vmcnt
    attn_fwd<<<4096, 64, 0, stream>>>(Qb, Kbf, Vt, AO);
    // output projection (proven 128^2)
    gemm_bt<0><<<1024, 256, 0, stream>>>(AO, Wot, 8192, 2048, 2048,
                                         out, nullptr, nullptr, nullptr, nullptr);
}

// Round 13
// 479.609 us; speedup vs baseline: 2.1039x; 1.2738x over previous
//
#include <hip/hip_runtime.h>
#include <hip/hip_bf16.h>
#include <stdint.h>

typedef unsigned short ushort_t;
typedef __bf16 bf16x8 __attribute__((ext_vector_type(8)));
typedef float    f32x4 __attribute__((ext_vector_type(4)));
typedef float   f32x16 __attribute__((ext_vector_type(16)));
typedef unsigned short us4 __attribute__((ext_vector_type(4)));
typedef unsigned int ui4 __attribute__((ext_vector_type(4)));

#define QK_SCALE 0.12751744f   /* log2(e) / sqrt(128) : folded into Q so softmax uses exp2 */
#define NEG_BIG  -1e30f

__device__ __forceinline__ unsigned short f2bf(float f) {
    union { float f; unsigned int u; } v; v.f = f;
    unsigned int u = v.u;
    return (unsigned short)((u + 0x7FFFu + ((u >> 16) & 1u)) >> 16);  // RNE
}

// HW packed convert: dst.lo = bf16(a), dst.hi = bf16(b)
__device__ __forceinline__ unsigned int pk2bf(float a, float b) {
    unsigned int r;
    asm("v_cvt_pk_bf16_f32 %0, %1, %2" : "=v"(r) : "v"(a), "v"(b));
    return r;
}

// async global->LDS, 16B per lane. LDS dest is wave-uniform base + lane*16.
__device__ __forceinline__ void gload16(const void* g, void* l) {
    __builtin_amdgcn_global_load_lds(
        (__attribute__((address_space(1))) void*)(uintptr_t)g,
        (__attribute__((address_space(3))) void*)(uint32_t)(uintptr_t)l,
        16, 0, 0);
}

// ---------------- prep kernels ----------------

__global__ __launch_bounds__(256) void cvt_bf16_kernel(
    const float4* __restrict__ in, us4* __restrict__ out, int n4) {
    int i = blockIdx.x * 256 + threadIdx.x;
    if (i >= n4) return;
    float4 v = in[i];
    us4 o; o[0] = f2bf(v.x); o[1] = f2bf(v.y); o[2] = f2bf(v.z); o[3] = f2bf(v.w);
    out[i] = o;
}

// in [R][C] fp32  ->  out [C][R] bf16   (64x64 LDS tile transpose)
__global__ __launch_bounds__(256) void transpose_bf16(
    const float* __restrict__ in, ushort_t* __restrict__ out, int R, int C) {
    __shared__ float t[64][65];
    int c0 = blockIdx.x * 64, r0 = blockIdx.y * 64;
    int cc = threadIdx.x & 63, rr = threadIdx.x >> 6;
#pragma unroll
    for (int i = 0; i < 16; ++i) {
        int r = i * 4 + rr;
        t[r][cc] = in[(size_t)(r0 + r) * C + c0 + cc];
    }
    __syncthreads();
#pragma unroll
    for (int i = 0; i < 16; ++i) {
        int r = i * 4 + rr;
        out[(size_t)(c0 + r) * R + r0 + cc] = f2bf(t[cc][r]);
    }
}

// rope table: [L][64] of (cos, sin)
__global__ __launch_bounds__(256) void rope_table_kernel(float2* __restrict__ rope) {
    int i = blockIdx.x * 256 + threadIdx.x;     // L*64 = 131072 exactly
    int l = i >> 6, j = i & 63;
    float inv = exp2f((float)j * -0.20762050593046f);  // 10000^(-j/64)
    float f = (float)l * inv;
    rope[i] = make_float2(cosf(f), sinf(f));
}

// ---------------- GEMM (proven 128^2):  C = A * Bt^T  (bf16 in, fp32 acc) ----------------

template <int EPI>
__global__ __launch_bounds__(256, 2)
void gemm_bt(const ushort_t* __restrict__ A, const ushort_t* __restrict__ Bt,
             int M, int N, int K,
             float* __restrict__ C,
             ushort_t* __restrict__ Qb, ushort_t* __restrict__ Kb,
             ushort_t* __restrict__ Vt, const float2* __restrict__ rope) {
    constexpr int MI = (EPI == 1) ? 2 : 4;
    constexpr int NI = (EPI == 1) ? 8 : 4;

    __shared__ __attribute__((aligned(16))) ushort_t ldsA[128 * 64];
    __shared__ __attribute__((aligned(16))) ushort_t ldsB[128 * 64];
    char* ldsAc = (char*)ldsA;
    char* ldsBc = (char*)ldsB;

    const int tid  = threadIdx.x;
    const int lane = tid & 63, wid = tid >> 6;
    const int lr = lane & 15, lg = lane >> 4;

    const int nbn = N >> 7;
    const int nwg = gridDim.x;
    const int bid = blockIdx.x;
    const int wg  = (bid & 7) * (nwg >> 3) + (bid >> 3);   // XCD-contiguous chunks
    const int bm  = wg / nbn, bn = wg % nbn;

    const int arow0 = (EPI == 1) ? wid * 32 : (wid >> 1) * 64;
    const int bcol0 = (EPI == 1) ? 0        : (wid & 1) * 64;

    const int colb = ((tid & 7) << 4) ^ (((tid >> 3) & 7) << 4);
    const int rowi = tid >> 3;                       // 0..31
    const char* Ap = (const char*)A + ((size_t)(bm * 128 + rowi) * K) * 2 + colb;
    const char* Bp = (const char*)Bt + ((size_t)(bn * 128 + rowi) * K) * 2 + colb;
    const size_t rstr = (size_t)32 * K * 2;
    char* ldA = ldsAc + wid * 1024;
    char* ldB = ldsBc + wid * 1024;

    f32x4 acc[MI][NI];
#pragma unroll
    for (int i = 0; i < MI; ++i)
#pragma unroll
        for (int j = 0; j < NI; ++j) acc[i][j] = (f32x4){0.f, 0.f, 0.f, 0.f};

    for (int k0 = 0; k0 < K; k0 += 64) {
#pragma unroll
        for (int r = 0; r < 4; ++r) {
            gload16(Ap + r * rstr + (size_t)k0 * 2, ldA + r * 4096);
            gload16(Bp + r * rstr + (size_t)k0 * 2, ldB + r * 4096);
        }
        __syncthreads();
#pragma unroll
        for (int kk = 0; kk < 2; ++kk) {
            bf16x8 af[MI], bfv[NI];
#pragma unroll
            for (int mi = 0; mi < MI; ++mi) {
                int row = arow0 + mi * 16 + lr;
                int off = (row << 7) + kk * 64 + lg * 16;
                off ^= (row & 7) << 4;
                af[mi] = *(const bf16x8*)(ldsAc + off);
            }
#pragma unroll
            for (int ni = 0; ni < NI; ++ni) {
                int row = bcol0 + ni * 16 + lr;
                int off = (row << 7) + kk * 64 + lg * 16;
                off ^= (row & 7) << 4;
                bfv[ni] = *(const bf16x8*)(ldsBc + off);
            }
#pragma unroll
            for (int mi = 0; mi < MI; ++mi)
#pragma unroll
                for (int ni = 0; ni < NI; ++ni)
                    acc[mi][ni] = __builtin_amdgcn_mfma_f32_16x16x32_bf16(
                        af[mi], bfv[ni], acc[mi][ni], 0, 0, 0);
        }
        __syncthreads();
    }

    if constexpr (EPI == 0) {
#pragma unroll
        for (int mi = 0; mi < MI; ++mi) {
            int gr0 = bm * 128 + arow0 + mi * 16 + lg * 4;
#pragma unroll
            for (int ni = 0; ni < NI; ++ni) {
                int gc = bn * 128 + bcol0 + ni * 16 + lr;
#pragma unroll
                for (int r = 0; r < 4; ++r)
                    C[(size_t)(gr0 + r) * N + gc] = acc[mi][ni][r];
            }
        }
    } else {
        const int which = bn >> 4, h = bn & 15;
#pragma unroll
        for (int mi = 0; mi < MI; ++mi) {
            int gr0 = bm * 128 + arow0 + mi * 16 + lg * 4;   // = b*L + l0 (4 consecutive l)
            int b = gr0 >> 11, l0 = gr0 & 2047;
            if (which == 2) {                                 // V -> [BH][D][L] (transposed)
#pragma unroll
                for (int ni = 0; ni < NI; ++ni) {
                    int d = ni * 16 + lr;
                    us4 pk;
#pragma unroll
                    for (int r = 0; r < 4; ++r) pk[r] = f2bf(acc[mi][ni][r]);
                    *(us4*)(Vt + ((size_t)(b * 16 + h) * 128 + d) * 2048 + l0) = pk;
                }
            } else {                                          // Q/K: rope, -> [BH][L][D]
                ushort_t* dst = (which == 0) ? Qb : Kb;
                const float sc = (which == 0) ? QK_SCALE : 1.0f;
#pragma unroll
                for (int ni = 0; ni < 4; ++ni) {
                    int j = ni * 16 + lr;                     // d < 64 ; pair at d+64 = frag ni+4
#pragma unroll
                    for (int r = 0; r < 4; ++r) {
                        float2 cs = rope[(size_t)(l0 + r) * 64 + j];
                        float x1 = acc[mi][ni][r], x2 = acc[mi][ni + 4][r];
                        size_t base = ((size_t)(b * 16 + h) * 2048 + (l0 + r)) * 128;
                        dst[base + j]      = f2bf((x1 * cs.x - x2 * cs.y) * sc);
                        dst[base + j + 64] = f2bf((x2 * cs.x + x1 * cs.y) * sc);
                    }
                }
            }
        }
    }
}

// ---------------- causal flash attention: 8-wave LDS-shared K/V ----------------
// Q,K: [BH][L][128] bf16 (Q pre-scaled); V^T: [BH][128][L] bf16; AO: [B][L][H*128] bf16.
// Block = 512 thr (8 waves) = one 256-row Q supertile of one head; wave w owns rows +32w
// and runs the R6-verified in-register softmax dataflow. K-tile [64][128] + V^T-tile
// [128][64] double-buffered in 64KB LDS, staged by all 8 waves (global_load_lds, source
// pre-swizzled, reads XOR-swizzled (row&7)<<4) -> 8x less VMEM traffic, LDS-class latency.
// Block = (head, pair p): supertile p then 7-p -> 36 tiles uniform; grid 256 = 1 block/CU.

__global__ __attribute__((amdgpu_flat_work_group_size(512, 512), amdgpu_waves_per_eu(2, 2)))
void attn_fwd(const ushort_t* __restrict__ Qb, const ushort_t* __restrict__ Kb,
              const ushort_t* __restrict__ Vt, ushort_t* __restrict__ AO) {
    constexpr int L = 2048;
    __shared__ __attribute__((aligned(16))) char smem[65536];   // [buf][K 16KB | V 16KB]

    const int tid  = threadIdx.x;
    const int lane = tid & 63, wid = tid >> 6;
    const int q_l  = lane & 31;
    const int hi   = lane >> 5;

    // 256 blocks: xcd = bid&7, hl = (bid>>3)&7, pair pr = bid>>6 (0..3)
    const int bid  = blockIdx.x;
    const int hl   = (bid >> 3) & 7;
    const int pr   = bid >> 6;
    const int head = (bid & 7) * 8 + hl;

    const ushort_t* Qh = Qb + (size_t)head * L * 128;
    const char*     KhB = (const char*)(Kb + (size_t)head * L * 128);
    const char*     VhB = (const char*)(Vt + (size_t)head * 128 * L);
    const int b = head >> 4, h = head & 15;

    // staging geometry (per-lane constants, tile-invariant)
    int rK[2], cK[2], rV[2], cV[2];
#pragma unroll
    for (int i = 0; i < 2; ++i) {
        rK[i] = wid * 8 + i * 4 + (lane >> 4);                    // K rows 0..63
        cK[i] = ((lane & 15) << 4) ^ ((rK[i] & 7) << 4);          // pre-swizzled src col
        rV[i] = wid * 16 + i * 8 + (lane >> 3);                   // V^T rows 0..127
        cV[i] = ((lane & 7) << 4) ^ ((rV[i] & 7) << 4);
    }
    const int kdst = wid * 2048;                                  // wave-uniform LDS offsets
    const int vdst = 16384 + wid * 2048;

    for (int ph = 0; ph < 2; ++ph) {
        const int s     = ph ? (7 - pr) : pr;
        const int q0w   = s * 256 + wid * 32;
        const int ntile = 4 * s + 4;

        // Q^T B-frags hoisted
        bf16x8 qf[8];
#pragma unroll
        for (int sb = 0; sb < 8; ++sb)
            qf[sb] = *(const bf16x8*)(Qh + (size_t)(q0w + q_l) * 128 + sb * 16 + hi * 8);

        f32x16 o[4];
#pragma unroll
        for (int d0 = 0; d0 < 4; ++d0) o[d0] = (f32x16)(0.f);
        float m_ = -__builtin_inff(), l_ = 0.f;

        __syncthreads();                        // phase boundary (buffers quiescent)
        // stage tile 0 -> buf 0
#pragma unroll
        for (int i = 0; i < 2; ++i) {
            gload16(KhB + (size_t)(rK[i]) * 256 + cK[i],              smem + kdst + i * 1024);
            gload16(VhB + (size_t)rV[i] * 4096 + cV[i],               smem + vdst + i * 1024);
        }

        for (int t = 0; t < ntile; ++t) {
            __syncthreads();                    // stage(t) landed (drains vmcnt + barrier)
            const int kb = (t & 1) * 32768;     // buffer holding tile t
            const int nb = ((t + 1) & 1) * 32768;
            if (t + 1 < ntile) {                // stage t+1 into other buffer
                const int kn = 64 * (t + 1);
#pragma unroll
                for (int i = 0; i < 2; ++i) {
                    gload16(KhB + (size_t)(kn + rK[i]) * 256 + cK[i], smem + nb + kdst + i * 1024);
                    gload16(VhB + (size_t)rV[i] * 4096 + (size_t)kn * 2 + cV[i], smem + nb + vdst + i * 1024);
                }
            }

            const int k0 = 64 * t;
            if (k0 > q0w + 31) continue;        // fully masked tile for this wave (uniform)

            const bool do1 = (k0 + 32 <= q0w + 31);

            // ---- S^T sub-tile 0: K rows k0..k0+31 from LDS ----
            f32x16 s0, s1;
            {
                bf16x8 kf[8];
#pragma unroll
                for (int sb = 0; sb < 8; ++sb) {
                    int off = kb + q_l * 256 + ((sb * 32 + hi * 16) ^ ((q_l & 7) << 4));
                    kf[sb] = *(const bf16x8*)(smem + off);
                }
                f32x16 sA = (f32x16)(0.f), sB = (f32x16)(0.f);
#pragma unroll
                for (int sb = 0; sb < 8; sb += 2) {
                    sA = __builtin_amdgcn_mfma_f32_32x32x16_bf16(kf[sb],     qf[sb],     sA, 0, 0, 0);
                    sB = __builtin_amdgcn_mfma_f32_32x32x16_bf16(kf[sb + 1], qf[sb + 1], sB, 0, 0, 0);
                }
                s0 = sA + sB;
            }
            if (do1) {                          // ---- sub-tile 1: rows k0+32..k0+63 ----
                bf16x8 kf[8];
#pragma unroll
                for (int sb = 0; sb < 8; ++sb) {
                    int off = kb + (32 + q_l) * 256 + ((sb * 32 + hi * 16) ^ ((q_l & 7) << 4));
                    kf[sb] = *(const bf16x8*)(smem + off);
                }
                f32x16 sA = (f32x16)(0.f), sB = (f32x16)(0.f);
#pragma unroll
                for (int sb = 0; sb < 8; sb += 2) {
                    sA = __builtin_amdgcn_mfma_f32_32x32x16_bf16(kf[sb],     qf[sb],     sA, 0, 0, 0);
                    sB = __builtin_amdgcn_mfma_f32_32x32x16_bf16(kf[sb + 1], qf[sb + 1], sB, 0, 0, 0);
                }
                s1 = sA + sB;
            }

            // ---- causal masks (wave-uniform guards) ----
            if (k0 + 31 > q0w) {
#pragma unroll
                for (int r = 0; r < 16; ++r) {
                    int crow = (r & 3) + 8 * (r >> 2) + 4 * hi;
                    if (k0 + crow > q0w + q_l) s0[r] = NEG_BIG;
                }
            }
            if (do1 && (k0 + 63 > q0w)) {
#pragma unroll
                for (int r = 0; r < 16; ++r) {
                    int crow = (r & 3) + 8 * (r >> 2) + 4 * hi;
                    if (k0 + 32 + crow > q0w + q_l) s1[r] = NEG_BIG;
                }
            }

            // ---- one softmax section per tile (lane owns q-row q0w+q_l) ----
            float t8[8];
#pragma unroll
            for (int r = 0; r < 8; ++r) t8[r] = fmaxf(s0[r], s0[r + 8]);
            if (do1)
#pragma unroll
                for (int r = 0; r < 8; ++r) t8[r] = fmaxf(t8[r], fmaxf(s1[r], s1[r + 8]));
#pragma unroll
            for (int r = 0; r < 4; ++r) t8[r] = fmaxf(t8[r], t8[r + 4]);
            float tmax = fmaxf(fmaxf(t8[0], t8[1]), fmaxf(t8[2], t8[3]));
            tmax = fmaxf(tmax, __shfl_xor(tmax, 32, 64));

            if (!__all(tmax <= m_ + 8.f)) {     // defer-max THR=8 (log2 units)
                float mn = fmaxf(m_, tmax);
                float alpha = exp2f(m_ - mn);
                m_ = mn;
                l_ *= alpha;
#pragma unroll
                for (int d0 = 0; d0 < 4; ++d0)
#pragma unroll
                    for (int r = 0; r < 16; ++r) o[d0][r] *= alpha;
            }

            float rs = 0.f;
#pragma unroll
            for (int r = 0; r < 16; ++r) { s0[r] = exp2f(s0[r] - m_); rs += s0[r]; }
            if (do1)
#pragma unroll
                for (int r = 0; r < 16; ++r) { s1[r] = exp2f(s1[r] - m_); rs += s1[r]; }
            rs += __shfl_xor(rs, 32, 64);
            l_ += rs;

            // ---- pack P -> bf16 B-frags via cvt_pk + partner exchange ----
            bf16x8 pfA[2], pfB[2];
            {
                unsigned int pk[8], po[8];
#pragma unroll
                for (int i = 0; i < 8; ++i) pk[i] = pk2bf(s0[2 * i], s0[2 * i + 1]);
#pragma unroll
                for (int i = 0; i < 8; ++i) po[i] = __shfl_xor(pk[i], 32, 64);
#pragma unroll
                for (int ks = 0; ks < 2; ++ks) {
                    ui4 dw;
                    dw[0] = hi ? po[ks * 4 + 2] : pk[ks * 4 + 0];
                    dw[1] = hi ? po[ks * 4 + 3] : pk[ks * 4 + 1];
                    dw[2] = hi ? pk[ks * 4 + 2] : po[ks * 4 + 0];
                    dw[3] = hi ? pk[ks * 4 + 3] : po[ks * 4 + 1];
                    pfA[ks] = __builtin_bit_cast(bf16x8, dw);
                }
            }
            if (do1) {
                unsigned int pk[8], po[8];
#pragma unroll
                for (int i = 0; i < 8; ++i) pk[i] = pk2bf(s1[2 * i], s1[2 * i + 1]);
#pragma unroll
                for (int i = 0; i < 8; ++i) po[i] = __shfl_xor(pk[i], 32, 64);
#pragma unroll
                for (int ks = 0; ks < 2; ++ks) {
                    ui4 dw;
                    dw[0] = hi ? po[ks * 4 + 2] : pk[ks * 4 + 0];
                    dw[1] = hi ? po[ks * 4 + 3] : pk[ks * 4 + 1];
                    dw[2] = hi ? pk[ks * 4 + 2] : po[ks * 4 + 0];
                    dw[3] = hi ? pk[ks * 4 + 3] : po[ks * 4 + 1];
                    pfB[ks] = __builtin_bit_cast(bf16x8, dw);
                }
            }

            // ---- O^T += V^T * P^T : V^T frags from LDS ----
            const int vb = kb + 16384;
#pragma unroll
            for (int d0 = 0; d0 < 4; ++d0) {
                int d = d0 * 32 + q_l;
#pragma unroll
                for (int ks = 0; ks < 2; ++ks) {
                    int off = vb + d * 128 + ((ks * 32 + hi * 16) ^ ((d & 7) << 4));
                    bf16x8 vf = *(const bf16x8*)(smem + off);
                    o[d0] = __builtin_amdgcn_mfma_f32_32x32x16_bf16(vf, pfA[ks], o[d0], 0, 0, 0);
                }
                if (do1) {
#pragma unroll
                    for (int ks = 0; ks < 2; ++ks) {
                        int off = vb + d * 128 + (((2 + ks) * 32 + hi * 16) ^ ((d & 7) << 4));
                        bf16x8 vf = *(const bf16x8*)(smem + off);
                        o[d0] = __builtin_amdgcn_mfma_f32_32x32x16_bf16(vf, pfB[ks], o[d0], 0, 0, 0);
                    }
                }
            }
        }

        // ---- epilogue: lane owns q-row q0w+q_l; d = d0*32 + (g*8 + hi*4 + 0..3) ----
        const float inv = 1.f / l_;
        const size_t rowbase = ((size_t)(b * 2048 + q0w + q_l)) * 2048 + h * 128;
#pragma unroll
        for (int d0 = 0; d0 < 4; ++d0)
#pragma unroll
            for (int g = 0; g < 4; ++g) {
                us4 v;
#pragma unroll
                for (int r = 0; r < 4; ++r) v[r] = f2bf(o[d0][g * 4 + r] * inv);
                *(us4*)(AO + rowbase + d0 * 32 + g * 8 + hi * 4) = v;
            }
    }
}

// ---------------- launcher ----------------

extern "C" void kernel_launch(void* const* d_in, const int* in_sizes, int n_in,
                              void* d_out, int out_size, void* d_ws, size_t ws_size,
                              hipStream_t stream) {
    const float* x    = (const float*)d_in[0];   // [4,2048,2048]
    const float* Wqkv = (const float*)d_in[1];   // [2048,6144]
    const float* Wo   = (const float*)d_in[2];   // [2048,2048]
    float* out = (float*)d_out;                  // [4,2048,2048] fp32

    char* w = (char*)d_ws;
    ushort_t* xb   = (ushort_t*)(w);               // x bf16             33,554,432 B
    ushort_t* W1t  = (ushort_t*)(w + 33554432);    // Wqkv^T bf16        25,165,824 B
    ushort_t* Wot  = (ushort_t*)(w + 58720256);    // Wo^T bf16           8,388,608 B
    ushort_t* Qb   = (ushort_t*)(w + 67108864);    // Q roped [BH][L][D] 33,554,432 B
    ushort_t* Kbf  = (ushort_t*)(w + 100663296);   // K roped [BH][L][D] 33,554,432 B
    ushort_t* Vt   = (ushort_t*)(w + 134217728);   // V^T    [BH][D][L]  33,554,432 B
    ushort_t* AO   = (ushort_t*)(w + 167772160);   // attn out bf16      33,554,432 B
    float2*   rope = (float2*)(w + 201326592);     // [L][64] cos/sin     1,048,576 B

    cvt_bf16_kernel<<<16384, 256, 0, stream>>>((const float4*)x, (us4*)xb, 4194304);
    transpose_bf16<<<dim3(96, 32), 256, 0, stream>>>(Wqkv, W1t, 2048, 6144);
    transpose_bf16<<<dim3(32, 32), 256, 0, stream>>>(Wo, Wot, 2048, 2048);
    rope_table_kernel<<<512, 256, 0, stream>>>(rope);

    // qkv GEMM (proven 128^2) + fused rope/reshape epilogue
    gemm_bt<1><<<3072, 256, 0, stream>>>(xb, W1t, 8192, 6144, 2048,
                                         nullptr, Qb, Kbf, Vt, rope);
    // causal flash attention: 8-wave blocks, LDS-shared K/V, paired supertiles
    attn_fwd<<<256, 512, 0, stream>>>(Qb, Kbf, Vt, AO);
    // output projection (proven 128^2)
    gemm_bt<0><<<1024, 256, 0, stream>>>(AO, Wot, 8192, 2048, 2048,
                                         out, nullptr, nullptr, nullptr, nullptr);
}

// Round 14
// 418.936 us; speedup vs baseline: 2.4086x; 1.1448x over previous
//
#include <hip/hip_runtime.h>
#include <hip/hip_bf16.h>
#include <stdint.h>

typedef unsigned short ushort_t;
typedef __bf16 bf16x8 __attribute__((ext_vector_type(8)));
typedef float    f32x4 __attribute__((ext_vector_type(4)));
typedef float   f32x16 __attribute__((ext_vector_type(16)));
typedef unsigned short us4 __attribute__((ext_vector_type(4)));
typedef unsigned int ui4 __attribute__((ext_vector_type(4)));

#define QK_SCALE 0.12751744f   /* log2(e) / sqrt(128) : folded into Q so softmax uses exp2 */
#define NEG_BIG  -1e30f

#define BARRIER() do { asm volatile("" ::: "memory"); __builtin_amdgcn_s_barrier(); asm volatile("" ::: "memory"); } while (0)
#define VMCNT(N)  asm volatile("s_waitcnt vmcnt(" #N ")" ::: "memory")
#define MFMA16(d, a, b) d = __builtin_amdgcn_mfma_f32_16x16x32_bf16(a, b, d, 0, 0, 0)

__device__ __forceinline__ unsigned short f2bf(float f) {
    union { float f; unsigned int u; } v; v.f = f;
    unsigned int u = v.u;
    return (unsigned short)((u + 0x7FFFu + ((u >> 16) & 1u)) >> 16);  // RNE
}

// HW packed convert: dst.lo = bf16(a), dst.hi = bf16(b)
__device__ __forceinline__ unsigned int pk2bf(float a, float b) {
    unsigned int r;
    asm("v_cvt_pk_bf16_f32 %0, %1, %2" : "=v"(r) : "v"(a), "v"(b));
    return r;
}

// async global->LDS, 16B per lane. LDS dest is wave-uniform base + lane*16.
__device__ __forceinline__ void gload16(const void* g, void* l) {
    __builtin_amdgcn_global_load_lds(
        (__attribute__((address_space(1))) void*)(uintptr_t)g,
        (__attribute__((address_space(3))) void*)(uint32_t)(uintptr_t)l,
        16, 0, 0);
}

// ---------------- prep kernels ----------------

__global__ __launch_bounds__(256) void cvt_bf16_kernel(
    const float4* __restrict__ in, us4* __restrict__ out, int n4) {
    int i = blockIdx.x * 256 + threadIdx.x;
    if (i >= n4) return;
    float4 v = in[i];
    us4 o; o[0] = f2bf(v.x); o[1] = f2bf(v.y); o[2] = f2bf(v.z); o[3] = f2bf(v.w);
    out[i] = o;
}

// generic: in [R][C] fp32 -> out [C][R] bf16
__global__ __launch_bounds__(256) void transpose_bf16(
    const float* __restrict__ in, ushort_t* __restrict__ out, int R, int C) {
    __shared__ float t[64][65];
    int c0 = blockIdx.x * 64, r0 = blockIdx.y * 64;
    int cc = threadIdx.x & 63, rr = threadIdx.x >> 6;
#pragma unroll
    for (int i = 0; i < 16; ++i) {
        int r = i * 4 + rr;
        t[r][cc] = in[(size_t)(r0 + r) * C + c0 + cc];
    }
    __syncthreads();
#pragma unroll
    for (int i = 0; i < 16; ++i) {
        int r = i * 4 + rr;
        out[(size_t)(c0 + r) * R + r0 + cc] = f2bf(t[cc][r]);
    }
}

// Wqkv transpose with Q/K head-dim bit-permutation: out col p pairs with p+16
// (orig pairs d,d+64). orig(p) = (p&15) | (((p>>5)&3)<<4) | (((p>>4)&1)<<6).
// QK^T is invariant to a consistent d-permutation of Q and K; V left unpermuted.
// (Verified in R8: absmax unchanged.)
__global__ __launch_bounds__(256) void transpose_wqkv(
    const float* __restrict__ in /*[2048][6144]*/, ushort_t* __restrict__ out /*[6144][2048]*/) {
    __shared__ float t[64][65];
    int c0 = blockIdx.x * 64, r0 = blockIdx.y * 64;
    int cc = threadIdx.x & 63, rr = threadIdx.x >> 6;
    int n = c0 + cc;
    int which = n >> 11;
    int src = n;
    if (which < 2) {
        int h = (n >> 7) & 15, p = n & 127;
        int po = (p & 15) | (((p >> 5) & 3) << 4) | (((p >> 4) & 1) << 6);
        src = (which << 11) + (h << 7) + po;
    }
#pragma unroll
    for (int i = 0; i < 16; ++i) {
        int r = i * 4 + rr;
        t[r][cc] = in[(size_t)(r0 + r) * 6144 + src];
    }
    __syncthreads();
#pragma unroll
    for (int i = 0; i < 16; ++i) {
        int r = i * 4 + rr;
        out[(size_t)(c0 + r) * 2048 + r0 + cc] = f2bf(t[cc][r]);
    }
}

// rope table: [L][64] of (cos, sin)
__global__ __launch_bounds__(256) void rope_table_kernel(float2* __restrict__ rope) {
    int i = blockIdx.x * 256 + threadIdx.x;     // L*64 = 131072 exactly
    int l = i >> 6, j = i & 63;
    float inv = exp2f((float)j * -0.20762050593046f);  // 10000^(-j/64)
    float f = (float)l * inv;
    rope[i] = make_float2(cosf(f), sinf(f));
}

// ---------------- 256x256 8-phase GEMM (live-set-engineered retry) ----------------
// BK=64, 512 thr (8 waves, 2M x 4N), wave tile 128x64. LDS 128 KiB: 2 bufs x (A0|A1|B0|B1).
// m-minor quadrant snake per K-tile: Q(lo,lo)->Q(hi,lo)->Q(hi,hi)->Q(lo,hi) so only ONE
// operand set is carried per phase (peak frag live = 48 regs vs R8's 80 -> no spill under
// the 128-arch-VGPR cap left by 128 AGPR acc). A_lo re-read from LDS at P4.
// Staging map re-derived for this read order (1-phase gap is safe: phase p's ds_reads
// drain at p's lgkmcnt before p's end barrier; stages issue at p+1 after that barrier):
//   P1: buf1.B1(to)  P2: buf1.A0c0,A1c0(to)  P3: buf0.A0c1,A1c1(te+2)  P4: buf0.B0(te+2)
//   P5: buf0.B1(te+2) P6: buf0.A0c0,A1c0(te+2) P7: buf1.A0c1,A1c1(to+2) P8: buf1.B0(to+2)
// vmcnt(4) at P4 (buf1 'to' complete) and P8 (buf0 te+2 complete); never 0 mid-loop.

template <int EPI>
__global__ __launch_bounds__(512, 2)
void gemm256(const ushort_t* __restrict__ A, const ushort_t* __restrict__ Bt,
             int M, int N, int K,
             float* __restrict__ C,
             ushort_t* __restrict__ Qb, ushort_t* __restrict__ Kb,
             ushort_t* __restrict__ Vt, const float2* __restrict__ rope) {
    __shared__ __attribute__((aligned(16))) char lds[131072];

    const int tid  = threadIdx.x;
    const int lane = tid & 63, wid = tid >> 6;
    const int lr = lane & 15, lg = lane >> 4;
    const int wr = wid >> 2, wc = wid & 3;        // wave grid 2(M) x 4(N)

    const int nbn = N >> 8;
    const int nwg = gridDim.x;
    const int bid = blockIdx.x;
    const int wg  = (bid & 7) * (nwg >> 3) + (bid >> 3);   // XCD-contiguous
    const int bm  = wg / nbn, bn = wg % nbn;

    // staging source (pre-swizzled col, matches read-side XOR)
    const int srow = tid >> 3;                                   // 0..63
    const int scol = ((tid & 7) << 4) ^ ((srow & 7) << 4);
    const size_t rowK2 = (size_t)K * 2;
    const char* sA0 = (const char*)A + ((size_t)(bm * 256 + srow)) * rowK2 + scol;
    const char* sA1 = sA0 + 128 * rowK2;
    const char* sB0 = (const char*)Bt + ((size_t)(bn * 256 + srow)) * rowK2 + scol;
    const char* sB1 = sB0 + 128 * rowK2;

    auto stg = [&](const char* s, int ch, int kt, int dst) {
        gload16(s + (size_t)(ch * 64) * rowK2 + (size_t)kt * 128, lds + dst + wid * 1024);
    };

    // read-side bases: off = row*128 + ((kk*64 + lg*16) ^ ((lr&7)<<4))  [R8-verified swizzle]
    const int xk0 = (lg * 16) ^ ((lr & 7) << 4);
    const int xk1 = (64 + lg * 16) ^ ((lr & 7) << 4);
    const int rowA = wr * 16384 + lr * 128;
    const int rowB = 32768 + (wc >> 1) * 16384 + ((wc & 1) * 64 + lr) * 128;

    auto rdA = [&](int bu, int mi, int kk) -> bf16x8 {
        return *(const bf16x8*)(lds + bu * 65536 + rowA + mi * 2048 + (kk ? xk1 : xk0));
    };
    auto rdB = [&](int bu, int ni, int kk) -> bf16x8 {
        return *(const bf16x8*)(lds + bu * 65536 + rowB + ni * 2048 + (kk ? xk1 : xk0));
    };

    f32x4 acc[8][4];
#pragma unroll
    for (int m = 0; m < 8; ++m)
#pragma unroll
        for (int n = 0; n < 4; ++n) acc[m][n] = (f32x4){0.f, 0.f, 0.f, 0.f};

    bf16x8 aF[4][2], bF[2][2];

#define RD_A(BU, MH) do { _Pragma("unroll") for (int mi = 0; mi < 4; ++mi) { \
        aF[mi][0] = rdA(BU, (MH)*4 + mi, 0); aF[mi][1] = rdA(BU, (MH)*4 + mi, 1); } } while (0)
#define RD_B(BU, NH) do { _Pragma("unroll") for (int ni = 0; ni < 2; ++ni) { \
        bF[ni][0] = rdB(BU, (NH)*2 + ni, 0); bF[ni][1] = rdB(BU, (NH)*2 + ni, 1); } } while (0)
#define QUAD(MH, NH) do { __builtin_amdgcn_s_setprio(1); \
        _Pragma("unroll") for (int kk = 0; kk < 2; ++kk) \
        _Pragma("unroll") for (int mi = 0; mi < 4; ++mi) \
        _Pragma("unroll") for (int ni = 0; ni < 2; ++ni) \
            MFMA16(acc[(MH)*4 + mi][(NH)*2 + ni], aF[mi][kk], bF[ni][kk]); \
        __builtin_amdgcn_s_setprio(0); } while (0)

    // ---- prologue: buf0 <- tile0 (8 chunks); buf1 <- tile1 {A0c1,A1c1,B0c0,B0c1} ----
    stg(sA0, 0, 0, 0);     stg(sA0, 1, 0, 8192);
    stg(sA1, 0, 0, 16384); stg(sA1, 1, 0, 24576);
    stg(sB0, 0, 0, 32768); stg(sB0, 1, 0, 40960);
    stg(sB1, 0, 0, 49152); stg(sB1, 1, 0, 57344);
    stg(sA0, 1, 1, 73728); stg(sA1, 1, 1, 90112);
    stg(sB0, 0, 1, 98304); stg(sB0, 1, 1, 106496);
    VMCNT(4);
    BARRIER();

    const int NIT = K / 128;
    for (int i = 0; i < NIT; ++i) {
        const int to = 2 * i + 1, te2 = 2 * i + 2, to2 = 2 * i + 3;
        const bool g = (i + 1 < NIT);

        // P1: reads buf0 A_lo + B_lo ; stage buf1.B1 (to)
        RD_A(0, 0); RD_B(0, 0);
        stg(sB1, 0, to, 114688); stg(sB1, 1, to, 122880);
        BARRIER(); QUAD(0, 0); BARRIER();

        // P2: reads buf0 A_hi (B_lo carried) ; stage buf1.A0c0,A1c0 (to)
        RD_A(0, 1);
        stg(sA0, 0, to, 65536); stg(sA1, 0, to, 81920);
        BARRIER(); QUAD(1, 0); BARRIER();

        // P3: reads buf0 B_hi (A_hi carried) ; stage buf0.A0c1,A1c1 (te+2)
        RD_B(0, 1);
        if (g) { stg(sA0, 1, te2, 8192); stg(sA1, 1, te2, 24576); }
        BARRIER(); QUAD(1, 1); BARRIER();

        // P4: re-reads buf0 A_lo (B_hi carried) ; stage buf0.B0 (te+2) ; buf1 'to' complete
        RD_A(0, 0);
        if (g) { stg(sB0, 0, te2, 32768); stg(sB0, 1, te2, 40960); VMCNT(4); }
        else   { VMCNT(0); }
        BARRIER(); QUAD(0, 1); BARRIER();

        // P5: reads buf1 A_lo + B_lo ; stage buf0.B1 (te+2)
        RD_A(1, 0); RD_B(1, 0);
        if (g) { stg(sB1, 0, te2, 49152); stg(sB1, 1, te2, 57344); }
        BARRIER(); QUAD(0, 0); BARRIER();

        // P6: reads buf1 A_hi ; stage buf0.A0c0,A1c0 (te+2)
        RD_A(1, 1);
        if (g) { stg(sA0, 0, te2, 0); stg(sA1, 0, te2, 16384); }
        BARRIER(); QUAD(1, 0); BARRIER();

        // P7: reads buf1 B_hi ; stage buf1.A0c1,A1c1 (to+2)
        RD_B(1, 1);
        if (g) { stg(sA0, 1, to2, 73728); stg(sA1, 1, to2, 90112); }
        BARRIER(); QUAD(1, 1); BARRIER();

        // P8: re-reads buf1 A_lo ; stage buf1.B0 (to+2) ; buf0 te+2 complete
        RD_A(1, 0);
        if (g) { stg(sB0, 0, to2, 98304); stg(sB0, 1, to2, 106496); VMCNT(4); }
        BARRIER(); QUAD(0, 1); BARRIER();
    }

#undef RD_A
#undef RD_B
#undef QUAD

    // ---------------- epilogue (R8-verified) ----------------
    if constexpr (EPI == 0) {
#pragma unroll
        for (int m = 0; m < 8; ++m) {
            int gr0 = bm * 256 + wr * 128 + m * 16 + lg * 4;
#pragma unroll
            for (int n = 0; n < 4; ++n) {
                int gc = bn * 256 + wc * 64 + n * 16 + lr;
#pragma unroll
                for (int r = 0; r < 4; ++r)
                    C[(size_t)(gr0 + r) * N + gc] = acc[m][n][r];
            }
        }
    } else {
        // head-chunk: 128 N-cols; wave covers 64 of them ((wc&1) half)
        const int hc = bn * 2 + (wc >> 1);       // 0..47
        const int which = hc >> 4, h = hc & 15;
#pragma unroll
        for (int m = 0; m < 8; ++m) {
            int gr0 = bm * 256 + wr * 128 + m * 16 + lg * 4;   // b*L + l0
            int b = gr0 >> 11, l0 = gr0 & 2047;
            if (which == 2) {                    // V -> [BH][D][L], d unpermuted
#pragma unroll
                for (int n = 0; n < 4; ++n) {
                    int d = (wc & 1) * 64 + n * 16 + lr;
                    us4 pk;
#pragma unroll
                    for (int r = 0; r < 4; ++r) pk[r] = f2bf(acc[m][n][r]);
                    *(us4*)(Vt + ((size_t)(b * 16 + h) * 128 + d) * 2048 + l0) = pk;
                }
            } else {                             // Q/K: rope on lane-local pairs (np, np+1)
                ushort_t* dst = (which == 0) ? Qb : Kb;
                const float sc = (which == 0) ? QK_SCALE : 1.0f;
#pragma unroll
                for (int np = 0; np < 4; np += 2) {
                    int tbl = ((wc & 1) * 2 + (np >> 1)) * 16 + lr;   // orig dim 0..63
                    int p1 = (wc & 1) * 64 + np * 16 + lr;            // permuted d
#pragma unroll
                    for (int r = 0; r < 4; ++r) {
                        float2 cs = rope[(size_t)(l0 + r) * 64 + tbl];
                        float x1 = acc[m][np][r], x2 = acc[m][np + 1][r];
                        size_t base = ((size_t)(b * 16 + h) * 2048 + (l0 + r)) * 128;
                        dst[base + p1]      = f2bf((x1 * cs.x - x2 * cs.y) * sc);
                        dst[base + p1 + 16] = f2bf((x2 * cs.x + x1 * cs.y) * sc);
                    }
                }
            }
        }
    }
}

// ---------------- causal flash attention: 8-wave LDS-shared K/V (R13, verified) ----------------
// NOTE: Q/K head-dims are bit-permuted consistently (transpose_wqkv) -> QK^T unchanged.

__global__ __attribute__((amdgpu_flat_work_group_size(512, 512), amdgpu_waves_per_eu(2, 2)))
void attn_fwd(const ushort_t* __restrict__ Qb, const ushort_t* __restrict__ Kb,
              const ushort_t* __restrict__ Vt, ushort_t* __restrict__ AO) {
    constexpr int L = 2048;
    __shared__ __attribute__((aligned(16))) char smem[65536];   // [buf][K 16KB | V 16KB]

    const int tid  = threadIdx.x;
    const int lane = tid & 63, wid = tid >> 6;
    const int q_l  = lane & 31;
    const int hi   = lane >> 5;

    // 256 blocks: xcd = bid&7, hl = (bid>>3)&7, pair pr = bid>>6 (0..3)
    const int bid  = blockIdx.x;
    const int hl   = (bid >> 3) & 7;
    const int pr   = bid >> 6;
    const int head = (bid & 7) * 8 + hl;

    const ushort_t* Qh = Qb + (size_t)head * L * 128;
    const char*     KhB = (const char*)(Kb + (size_t)head * L * 128);
    const char*     VhB = (const char*)(Vt + (size_t)head * 128 * L);
    const int b = head >> 4, h = head & 15;

    // staging geometry (per-lane constants, tile-invariant)
    int rK[2], cK[2], rV[2], cV[2];
#pragma unroll
    for (int i = 0; i < 2; ++i) {
        rK[i] = wid * 8 + i * 4 + (lane >> 4);                    // K rows 0..63
        cK[i] = ((lane & 15) << 4) ^ ((rK[i] & 7) << 4);          // pre-swizzled src col
        rV[i] = wid * 16 + i * 8 + (lane >> 3);                   // V^T rows 0..127
        cV[i] = ((lane & 7) << 4) ^ ((rV[i] & 7) << 4);
    }
    const int kdst = wid * 2048;                                  // wave-uniform LDS offsets
    const int vdst = 16384 + wid * 2048;

    for (int ph = 0; ph < 2; ++ph) {
        const int s     = ph ? (7 - pr) : pr;
        const int q0w   = s * 256 + wid * 32;
        const int ntile = 4 * s + 4;

        // Q^T B-frags hoisted
        bf16x8 qf[8];
#pragma unroll
        for (int sb = 0; sb < 8; ++sb)
            qf[sb] = *(const bf16x8*)(Qh + (size_t)(q0w + q_l) * 128 + sb * 16 + hi * 8);

        f32x16 o[4];
#pragma unroll
        for (int d0 = 0; d0 < 4; ++d0) o[d0] = (f32x16)(0.f);
        float m_ = -__builtin_inff(), l_ = 0.f;

        __syncthreads();                        // phase boundary (buffers quiescent)
        // stage tile 0 -> buf 0
#pragma unroll
        for (int i = 0; i < 2; ++i) {
            gload16(KhB + (size_t)(rK[i]) * 256 + cK[i],              smem + kdst + i * 1024);
            gload16(VhB + (size_t)rV[i] * 4096 + cV[i],               smem + vdst + i * 1024);
        }

        for (int t = 0; t < ntile; ++t) {
            __syncthreads();                    // stage(t) landed (drains vmcnt + barrier)
            const int kb = (t & 1) * 32768;     // buffer holding tile t
            const int nb = ((t + 1) & 1) * 32768;
            if (t + 1 < ntile) {                // stage t+1 into other buffer
                const int kn = 64 * (t + 1);
#pragma unroll
                for (int i = 0; i < 2; ++i) {
                    gload16(KhB + (size_t)(kn + rK[i]) * 256 + cK[i], smem + nb + kdst + i * 1024);
                    gload16(VhB + (size_t)rV[i] * 4096 + (size_t)kn * 2 + cV[i], smem + nb + vdst + i * 1024);
                }
            }

            const int k0 = 64 * t;
            if (k0 > q0w + 31) continue;        // fully masked tile for this wave (uniform)

            const bool do1 = (k0 + 32 <= q0w + 31);

            // ---- S^T sub-tile 0: K rows k0..k0+31 from LDS ----
            f32x16 s0, s1;
            {
                bf16x8 kf[8];
#pragma unroll
                for (int sb = 0; sb < 8; ++sb) {
                    int off = kb + q_l * 256 + ((sb * 32 + hi * 16) ^ ((q_l & 7) << 4));
                    kf[sb] = *(const bf16x8*)(smem + off);
                }
                f32x16 sA = (f32x16)(0.f), sB = (f32x16)(0.f);
#pragma unroll
                for (int sb = 0; sb < 8; sb += 2) {
                    sA = __builtin_amdgcn_mfma_f32_32x32x16_bf16(kf[sb],     qf[sb],     sA, 0, 0, 0);
                    sB = __builtin_amdgcn_mfma_f32_32x32x16_bf16(kf[sb + 1], qf[sb + 1], sB, 0, 0, 0);
                }
                s0 = sA + sB;
            }
            if (do1) {                          // ---- sub-tile 1: rows k0+32..k0+63 ----
                bf16x8 kf[8];
#pragma unroll
                for (int sb = 0; sb < 8; ++sb) {
                    int off = kb + (32 + q_l) * 256 + ((sb * 32 + hi * 16) ^ ((q_l & 7) << 4));
                    kf[sb] = *(const bf16x8*)(smem + off);
                }
                f32x16 sA = (f32x16)(0.f), sB = (f32x16)(0.f);
#pragma unroll
                for (int sb = 0; sb < 8; sb += 2) {
                    sA = __builtin_amdgcn_mfma_f32_32x32x16_bf16(kf[sb],     qf[sb],     sA, 0, 0, 0);
                    sB = __builtin_amdgcn_mfma_f32_32x32x16_bf16(kf[sb + 1], qf[sb + 1], sB, 0, 0, 0);
                }
                s1 = sA + sB;
            }

            // ---- causal masks (wave-uniform guards) ----
            if (k0 + 31 > q0w) {
#pragma unroll
                for (int r = 0; r < 16; ++r) {
                    int crow = (r & 3) + 8 * (r >> 2) + 4 * hi;
                    if (k0 + crow > q0w + q_l) s0[r] = NEG_BIG;
                }
            }
            if (do1 && (k0 + 63 > q0w)) {
#pragma unroll
                for (int r = 0; r < 16; ++r) {
                    int crow = (r & 3) + 8 * (r >> 2) + 4 * hi;
                    if (k0 + 32 + crow > q0w + q_l) s1[r] = NEG_BIG;
                }
            }

            // ---- one softmax section per tile (lane owns q-row q0w+q_l) ----
            float t8[8];
#pragma unroll
            for (int r = 0; r < 8; ++r) t8[r] = fmaxf(s0[r], s0[r + 8]);
            if (do1)
#pragma unroll
                for (int r = 0; r < 8; ++r) t8[r] = fmaxf(t8[r], fmaxf(s1[r], s1[r + 8]));
#pragma unroll
            for (int r = 0; r < 4; ++r) t8[r] = fmaxf(t8[r], t8[r + 4]);
            float tmax = fmaxf(fmaxf(t8[0], t8[1]), fmaxf(t8[2], t8[3]));
            tmax = fmaxf(tmax, __shfl_xor(tmax, 32, 64));

            if (!__all(tmax <= m_ + 8.f)) {     // defer-max THR=8 (log2 units)
                float mn = fmaxf(m_, tmax);
                float alpha = exp2f(m_ - mn);
                m_ = mn;
                l_ *= alpha;
#pragma unroll
                for (int d0 = 0; d0 < 4; ++d0)
#pragma unroll
                    for (int r = 0; r < 16; ++r) o[d0][r] *= alpha;
            }

            float rs = 0.f;
#pragma unroll
            for (int r = 0; r < 16; ++r) { s0[r] = exp2f(s0[r] - m_); rs += s0[r]; }
            if (do1)
#pragma unroll
                for (int r = 0; r < 16; ++r) { s1[r] = exp2f(s1[r] - m_); rs += s1[r]; }
            rs += __shfl_xor(rs, 32, 64);
            l_ += rs;

            // ---- pack P -> bf16 B-frags via cvt_pk + partner exchange ----
            bf16x8 pfA[2], pfB[2];
            {
                unsigned int pk[8], po[8];
#pragma unroll
                for (int i = 0; i < 8; ++i) pk[i] = pk2bf(s0[2 * i], s0[2 * i + 1]);
#pragma unroll
                for (int i = 0; i < 8; ++i) po[i] = __shfl_xor(pk[i], 32, 64);
#pragma unroll
                for (int ks = 0; ks < 2; ++ks) {
                    ui4 dw;
                    dw[0] = hi ? po[ks * 4 + 2] : pk[ks * 4 + 0];
                    dw[1] = hi ? po[ks * 4 + 3] : pk[ks * 4 + 1];
                    dw[2] = hi ? pk[ks * 4 + 2] : po[ks * 4 + 0];
                    dw[3] = hi ? pk[ks * 4 + 3] : po[ks * 4 + 1];
                    pfA[ks] = __builtin_bit_cast(bf16x8, dw);
                }
            }
            if (do1) {
                unsigned int pk[8], po[8];
#pragma unroll
                for (int i = 0; i < 8; ++i) pk[i] = pk2bf(s1[2 * i], s1[2 * i + 1]);
#pragma unroll
                for (int i = 0; i < 8; ++i) po[i] = __shfl_xor(pk[i], 32, 64);
#pragma unroll
                for (int ks = 0; ks < 2; ++ks) {
                    ui4 dw;
                    dw[0] = hi ? po[ks * 4 + 2] : pk[ks * 4 + 0];
                    dw[1] = hi ? po[ks * 4 + 3] : pk[ks * 4 + 1];
                    dw[2] = hi ? pk[ks * 4 + 2] : po[ks * 4 + 0];
                    dw[3] = hi ? pk[ks * 4 + 3] : po[ks * 4 + 1];
                    pfB[ks] = __builtin_bit_cast(bf16x8, dw);
                }
            }

            // ---- O^T += V^T * P^T : V^T frags from LDS ----
            const int vb = kb + 16384;
#pragma unroll
            for (int d0 = 0; d0 < 4; ++d0) {
                int d = d0 * 32 + q_l;
#pragma unroll
                for (int ks = 0; ks < 2; ++ks) {
                    int off = vb + d * 128 + ((ks * 32 + hi * 16) ^ ((d & 7) << 4));
                    bf16x8 vf = *(const bf16x8*)(smem + off);
                    o[d0] = __builtin_amdgcn_mfma_f32_32x32x16_bf16(vf, pfA[ks], o[d0], 0, 0, 0);
                }
                if (do1) {
#pragma unroll
                    for (int ks = 0; ks < 2; ++ks) {
                        int off = vb + d * 128 + (((2 + ks) * 32 + hi * 16) ^ ((d & 7) << 4));
                        bf16x8 vf = *(const bf16x8*)(smem + off);
                        o[d0] = __builtin_amdgcn_mfma_f32_32x32x16_bf16(vf, pfB[ks], o[d0], 0, 0, 0);
                    }
                }
            }
        }

        // ---- epilogue: lane owns q-row q0w+q_l; d = d0*32 + (g*8 + hi*4 + 0..3) ----
        const float inv = 1.f / l_;
        const size_t rowbase = ((size_t)(b * 2048 + q0w + q_l)) * 2048 + h * 128;
#pragma unroll
        for (int d0 = 0; d0 < 4; ++d0)
#pragma unroll
            for (int g = 0; g < 4; ++g) {
                us4 v;
#pragma unroll
                for (int r = 0; r < 4; ++r) v[r] = f2bf(o[d0][g * 4 + r] * inv);
                *(us4*)(AO + rowbase + d0 * 32 + g * 8 + hi * 4) = v;
            }
    }
}

// ---------------- launcher ----------------

extern "C" void kernel_launch(void* const* d_in, const int* in_sizes, int n_in,
                              void* d_out, int out_size, void* d_ws, size_t ws_size,
                              hipStream_t stream) {
    const float* x    = (const float*)d_in[0];   // [4,2048,2048]
    const float* Wqkv = (const float*)d_in[1];   // [2048,6144]
    const float* Wo   = (const float*)d_in[2];   // [2048,2048]
    float* out = (float*)d_out;                  // [4,2048,2048] fp32

    char* w = (char*)d_ws;
    ushort_t* xb   = (ushort_t*)(w);               // x bf16             33,554,432 B
    ushort_t* W1t  = (ushort_t*)(w + 33554432);    // Wqkv^T bf16 (QK-permuted) 25,165,824 B
    ushort_t* Wot  = (ushort_t*)(w + 58720256);    // Wo^T bf16           8,388,608 B
    ushort_t* Qb   = (ushort_t*)(w + 67108864);    // Q roped [BH][L][D'] 33,554,432 B
    ushort_t* Kbf  = (ushort_t*)(w + 100663296);   // K roped [BH][L][D'] 33,554,432 B
    ushort_t* Vt   = (ushort_t*)(w + 134217728);   // V^T    [BH][D][L]  33,554,432 B
    ushort_t* AO   = (ushort_t*)(w + 167772160);   // attn out bf16      33,554,432 B
    float2*   rope = (float2*)(w + 201326592);     // [L][64] cos/sin     1,048,576 B

    cvt_bf16_kernel<<<16384, 256, 0, stream>>>((const float4*)x, (us4*)xb, 4194304);
    transpose_wqkv<<<dim3(96, 32), 256, 0, stream>>>(Wqkv, W1t);
    transpose_bf16<<<dim3(32, 32), 256, 0, stream>>>(Wo, Wot, 2048, 2048);
    rope_table_kernel<<<512, 256, 0, stream>>>(rope);

    // qkv GEMM (256^2 8-phase, live-set-engineered) + fused rope/reshape epilogue
    gemm256<1><<<768, 512, 0, stream>>>(xb, W1t, 8192, 6144, 2048,
                                        nullptr, Qb, Kbf, Vt, rope);
    // causal flash attention: 8-wave blocks, LDS-shared K/V (R13, verified)
    attn_fwd<<<256, 512, 0, stream>>>(Qb, Kbf, Vt, AO);
    // output projection (256^2 8-phase)
    gemm256<0><<<256, 512, 0, stream>>>(AO, Wot, 8192, 2048, 2048,
                                        out, nullptr, nullptr, nullptr, nullptr);
}